// Round 6
// baseline (12795.544 us; speedup 1.0000x reference)
//
#include <hip/hip_runtime.h>
#include <hip/hip_bf16.h>
#include <math.h>

typedef _Float16 f16x8 __attribute__((ext_vector_type(8)));
typedef float    f32x4 __attribute__((ext_vector_type(4)));

#define DEV __device__ __forceinline__

static constexpr int Ee   = 300;   // glove dim
static constexpr int INP  = 303;   // E + 3
static constexpr int INPP = 320;   // padded input dim
static constexpr int Hh   = 512;
static constexpr int Bb   = 64;
static constexpr int Tt   = 512;
static constexpr int D2H  = 1024;  // 2H
static constexpr int SLAB = Bb * Hh;  // one h-state slab (elements)

typedef const void __attribute__((address_space(1)))* gas_t;
typedef void __attribute__((address_space(3)))* las_t;

// ---- MFMA fragment load: K-major matrix M[row][k], frag[l][j] = M[row0+(l&15)][k0+8*(l>>4)+j]
DEV f16x8 ldfrag(const _Float16* base, int ld, int row0, int k0, int lane) {
  return *reinterpret_cast<const f16x8*>(base + (size_t)(row0 + (lane & 15)) * ld + (k0 + 8 * (lane >> 4)));
}
DEV float sigm(float x) { return 1.0f / (1.0f + expf(-x)); }

// ---------------- weight convert (f32 -> f16, optional column pad) ----------------
__global__ void convert_pad(const float* __restrict__ src, _Float16* __restrict__ dst,
                            int rows, int csrc, int cdst) {
  int i = blockIdx.x * 256 + threadIdx.x;
  if (i >= rows * cdst) return;
  int r = i / cdst, c = i - r * cdst;
  dst[i] = (c < csrc) ? (_Float16)src[(size_t)r * csrc + c] : (_Float16)0.0f;
}

// ---------------- embedding: xt (T, B, INPP) f16 ----------------
__global__ void embed_kernel(const int* __restrict__ context, const int* __restrict__ tags,
                             const float* __restrict__ glove, const float* __restrict__ bio,
                             _Float16* __restrict__ xt) {
  int blk = blockIdx.x;            // t*64 + b
  int t = blk >> 6, b = blk & 63;
  int cid = context[b * Tt + t];   // context (B,T,1)
  int tag = tags[b * Tt + t];      // (B,T)
  _Float16* dst = xt + (size_t)blk * INPP;
  for (int c = threadIdx.x; c < INPP; c += 64) {
    float v = (c < Ee) ? glove[(size_t)cid * Ee + c]
                       : ((c < INP) ? bio[tag * 3 + (c - Ee)] : 0.0f);
    dst[c] = (_Float16)v;
  }
}

// ---------------- persistent GRU recurrence: fwd+bwd interleaved per block ----------------
// unit = layer*2 + dir. hb slabs: hb + ((size_t)t*4 + unit)*SLAB holds h_{t-1}
// (slab t=0 zeros). Step t reads slab t, write-through publishes slab t+1.
struct GruParams {
  const _Float16* xt;
  const _Float16* Wx[4];   // input-side weights (ld = 320 for L1, 512 for L2)
  const _Float16* Wh[4];   // hidden-side weights (ld = 512)
  const float* bih[4];
  const float* bhh[4];
  _Float16* hb;            // fresh h16 slabs, (Tt+1) x 4 x SLAB
  _Float16* allh;          // (B, T, 2H) f16
  float*    h1fin;         // [dir][64][512] fp32 layer-1 final states
};

// stage a 64KB slab (64x512 f16) into LDS, linear dest, inverse-swizzled source.
DEV void stage64k(const char* __restrict__ gsrc, char* lbase, int tid) {
#pragma unroll
  for (int it = 0; it < 16; ++it) {
    int o = (it * 256 + tid) * 16;
    int row = o >> 10, boff = o & 1023;
    int srcOff = (row << 10) | (boff ^ ((row & 7) << 4));
    __builtin_amdgcn_global_load_lds((gas_t)(gsrc + srcOff), (las_t)(lbase + o), 16, 0, 0);
  }
}

// A-fragment read from a staged+swizzled 64x512 f16 LDS slab
DEV f16x8 ldsfrag(const char* lbase, int mt, int k0, int lane) {
  int row = mt * 16 + (lane & 15);
  int b = (k0 + 8 * (lane >> 4)) * 2;
  int addr = (row << 10) + (b ^ ((row & 7) << 4));
  return *reinterpret_cast<const f16x8*>(lbase + addr);
}

DEV void hside(f32x4* acc, const char* ldsbuf, const f16x8* wh, int lane) {
#pragma unroll
  for (int k = 0; k < 16; ++k)
#pragma unroll
    for (int mt = 0; mt < 4; ++mt)
      acc[mt] = __builtin_amdgcn_mfma_f32_16x16x32_f16(
          ldsfrag(ldsbuf, mt, k * 32, lane), wh[k], acc[mt], 0, 0, 0);
}

__global__ __launch_bounds__(256, 1) void gru_persist(GruParams P, unsigned* flags) {
  int layer = blockIdx.x >> 5;        // 0 or 1
  int blk   = blockIdx.x & 31;
  int cb    = blk << 4;               // h-column base
  int uf = layer * 2, ub = layer * 2 + 1;
  unsigned* flagF = flags + ((size_t)uf * 32 + blk) * 16;   // 64B/flag
  unsigned* flagB = flags + ((size_t)ub * 32 + blk) * 16;
  const unsigned* ownFf = flags + (size_t)uf * 32 * 16;
  const unsigned* ownFb = flags + (size_t)ub * 32 * 16;
  const unsigned* l1Ff  = flags;                            // unit 0
  const unsigned* l1Fb  = flags + (size_t)32 * 16;          // unit 1

  int tid = threadIdx.x, w = tid >> 6, lane = tid & 63;
  // wave roles: 0 -> r, 1 -> z, 2 -> n_i (x-side only), 3 -> n_h (h-side only)
  int nrow = ((w == 0) ? 0 : (w == 1) ? Hh : 2 * Hh) + cb;
  int col = lane & 15;

  const float* bihF = P.bih[uf]; const float* bhhF = P.bhh[uf];
  const float* bihB = P.bih[ub]; const float* bhhB = P.bhh[ub];
  float bvF, bvB;
  if      (w == 0) { bvF = bihF[cb+col]+bhhF[cb+col];           bvB = bihB[cb+col]+bhhB[cb+col]; }
  else if (w == 1) { bvF = bihF[Hh+cb+col]+bhhF[Hh+cb+col];     bvB = bihB[Hh+cb+col]+bhhB[Hh+cb+col]; }
  else if (w == 2) { bvF = bihF[2*Hh+cb+col];                   bvB = bihB[2*Hh+cb+col]; }
  else             { bvF = bhhF[2*Hh+cb+col];                   bvB = bhhB[2*Hh+cb+col]; }

  __shared__ _Float16 ldsHf[SLAB];    // 64KB fwd hprev
  __shared__ _Float16 ldsHb[SLAB];    // 64KB bwd hprev
  __shared__ float gl[4][64][20];     // gate pre-activations (shared f/b, sequenced)
  __shared__ float h32s[2][64][17];   // block-private fp32 h state per dir
  for (int e = tid; e < 2 * 64 * 17; e += 256) ((float*)h32s)[e] = 0.0f;
  __syncthreads();

  int rbase = 4 * (lane >> 4);
  int erow = tid >> 2, ec0 = (tid & 3) << 2;  // epilogue: 4 cols/thread

#define GLWRITE(ACC, BV)                                          \
  _Pragma("unroll")                                               \
  for (int mt = 0; mt < 4; ++mt)                                  \
    _Pragma("unroll")                                             \
    for (int r = 0; r < 4; ++r)                                   \
      gl[w][mt * 16 + rbase + r][col] = (ACC)[mt][r] + (BV);

#define EPILOGUE(DIRI, HV, PK)                                    \
  _Pragma("unroll")                                               \
  for (int j = 0; j < 4; ++j) {                                   \
    int c = ec0 + j;                                              \
    float rr = sigm(gl[0][erow][c]);                              \
    float zz = sigm(gl[1][erow][c]);                              \
    float nn = tanhf(gl[2][erow][c] + rr * gl[3][erow][c]);       \
    float hp = h32s[DIRI][erow][c];                               \
    (HV)[j] = (1.0f - zz) * nn + zz * hp;                         \
    h32s[DIRI][erow][c] = (HV)[j];                                \
    (PK).h[j] = (_Float16)(HV)[j];                                \
  }

  union PkU { _Float16 h[4]; unsigned long long u; };

  if (layer == 0) {
    f16x8 wxf[10], whf[16], wxb[10], whb[16];
    if (w != 3) {
#pragma unroll
      for (int k = 0; k < 10; ++k) wxf[k] = ldfrag(P.Wx[0], INPP, nrow, k * 32, lane);
#pragma unroll
      for (int k = 0; k < 10; ++k) wxb[k] = ldfrag(P.Wx[1], INPP, nrow, k * 32, lane);
    }
    if (w != 2) {
#pragma unroll
      for (int k = 0; k < 16; ++k) whf[k] = ldfrag(P.Wh[0], Hh, nrow, k * 32, lane);
#pragma unroll
      for (int k = 0; k < 16; ++k) whb[k] = ldfrag(P.Wh[1], Hh, nrow, k * 32, lane);
    }
    for (int t = 0; t < Tt; ++t) {
      // ================= F segment (dir 0) =================
      if (tid < 32) {
        const unsigned* p = ownFf + tid * 16;
        while (__hip_atomic_load(p, __ATOMIC_RELAXED, __HIP_MEMORY_SCOPE_AGENT) < (unsigned)t)
          __builtin_amdgcn_s_sleep(1);
      }
      __syncthreads();
      stage64k((const char*)(P.hb + ((size_t)t * 4 + 0) * SLAB), (char*)ldsHf, tid);
      f32x4 acc[4] = {};
      if (w != 3) {
        const _Float16* arow = P.xt + (size_t)t * Bb * INPP + (lane & 15) * INPP + 8 * (lane >> 4);
#pragma unroll
        for (int k = 0; k < 10; ++k)
#pragma unroll
          for (int mt = 0; mt < 4; ++mt)
            acc[mt] = __builtin_amdgcn_mfma_f32_16x16x32_f16(
                *(const f16x8*)(arow + mt * 16 * INPP + k * 32), wxf[k], acc[mt], 0, 0, 0);
      }
      asm volatile("s_waitcnt vmcnt(0)" ::: "memory");
      __syncthreads();
      if (w != 2) hside(acc, (const char*)ldsHf, whf, lane);
      GLWRITE(acc, bvF);
      __syncthreads();
      PkU pkf; float hvf[4];
      EPILOGUE(0, hvf, pkf);
      _Float16* houtF = P.hb + ((size_t)(t + 1) * 4 + 0) * SLAB + erow * Hh + cb + ec0;
      __hip_atomic_store((unsigned long long*)houtF, pkf.u, __ATOMIC_RELAXED, __HIP_MEMORY_SCOPE_AGENT);
      if (t == Tt - 1)
        *(float4*)(P.h1fin + ((size_t)0 * Bb + erow) * Hh + cb + ec0) = make_float4(hvf[0], hvf[1], hvf[2], hvf[3]);

      // ================= B segment (dir 1) =================
      if (tid < 32) {
        const unsigned* p = ownFb + tid * 16;
        while (__hip_atomic_load(p, __ATOMIC_RELAXED, __HIP_MEMORY_SCOPE_AGENT) < (unsigned)t)
          __builtin_amdgcn_s_sleep(1);
      }
      __syncthreads();                 // also fences gl reads (epi F) before B's gl writes
      stage64k((const char*)(P.hb + ((size_t)t * 4 + 1) * SLAB), (char*)ldsHb, tid);
      f32x4 acc2[4] = {};
      if (w != 3) {
        const _Float16* arow = P.xt + (size_t)(Tt - 1 - t) * Bb * INPP + (lane & 15) * INPP + 8 * (lane >> 4);
#pragma unroll
        for (int k = 0; k < 10; ++k)
#pragma unroll
          for (int mt = 0; mt < 4; ++mt)
            acc2[mt] = __builtin_amdgcn_mfma_f32_16x16x32_f16(
                *(const f16x8*)(arow + mt * 16 * INPP + k * 32), wxb[k], acc2[mt], 0, 0, 0);
      }
      asm volatile("s_waitcnt vmcnt(0)" ::: "memory");   // drains B stage + F epilogue stores
      __syncthreads();
      if (tid == 0)
        __hip_atomic_store(flagF, (unsigned)(t + 1), __ATOMIC_RELAXED, __HIP_MEMORY_SCOPE_AGENT);
      if (w != 2) hside(acc2, (const char*)ldsHb, whb, lane);
      GLWRITE(acc2, bvB);
      __syncthreads();
      PkU pkb; float hvb[4];
      EPILOGUE(1, hvb, pkb);
      _Float16* houtB = P.hb + ((size_t)(t + 1) * 4 + 1) * SLAB + erow * Hh + cb + ec0;
      __hip_atomic_store((unsigned long long*)houtB, pkb.u, __ATOMIC_RELAXED, __HIP_MEMORY_SCOPE_AGENT);
      if (t == Tt - 1)
        *(float4*)(P.h1fin + ((size_t)1 * Bb + erow) * Hh + cb + ec0) = make_float4(hvb[0], hvb[1], hvb[2], hvb[3]);
      asm volatile("s_waitcnt vmcnt(0)" ::: "memory");
      __syncthreads();
      if (tid == 0)
        __hip_atomic_store(flagB, (unsigned)(t + 1), __ATOMIC_RELAXED, __HIP_MEMORY_SCOPE_AGENT);
    }
  } else {
    f16x8 wxf[16], whf[16], wxb[16], whb[16];
    if (w != 3) {
#pragma unroll
      for (int k = 0; k < 16; ++k) wxf[k] = ldfrag(P.Wx[2], Hh, nrow, k * 32, lane);
#pragma unroll
      for (int k = 0; k < 16; ++k) wxb[k] = ldfrag(P.Wx[3], Hh, nrow, k * 32, lane);
    }
    if (w != 2) {
#pragma unroll
      for (int k = 0; k < 16; ++k) whf[k] = ldfrag(P.Wh[2], Hh, nrow, k * 32, lane);
#pragma unroll
      for (int k = 0; k < 16; ++k) whb[k] = ldfrag(P.Wh[3], Hh, nrow, k * 32, lane);
    }
    for (int t = 0; t < Tt; ++t) {
      // ================= F segment (dir 0) =================
      if (tid < 32) {
        const unsigned* p = ownFf + tid * 16;
        while (__hip_atomic_load(p, __ATOMIC_RELAXED, __HIP_MEMORY_SCOPE_AGENT) < (unsigned)t)
          __builtin_amdgcn_s_sleep(1);
      } else if (tid < 64) {
        const unsigned* p = l1Ff + (tid - 32) * 16;
        while (__hip_atomic_load(p, __ATOMIC_RELAXED, __HIP_MEMORY_SCOPE_AGENT) < (unsigned)(t + 1))
          __builtin_amdgcn_s_sleep(1);
      }
      __syncthreads();
      stage64k((const char*)(P.hb + ((size_t)t * 4 + 2) * SLAB), (char*)ldsHf, tid);
      f32x4 acc[4] = {};
      if (w != 3) {  // x-side: h1_f(t) direct from global (fresh slab, LLC)
        const _Float16* xr = P.hb + ((size_t)(t + 1) * 4 + 0) * SLAB + (lane & 15) * Hh + 8 * (lane >> 4);
#pragma unroll
        for (int k = 0; k < 16; ++k)
#pragma unroll
          for (int mt = 0; mt < 4; ++mt)
            acc[mt] = __builtin_amdgcn_mfma_f32_16x16x32_f16(
                *(const f16x8*)(xr + mt * 16 * Hh + k * 32), wxf[k], acc[mt], 0, 0, 0);
      }
      asm volatile("s_waitcnt vmcnt(0)" ::: "memory");
      __syncthreads();
      if (w != 2) hside(acc, (const char*)ldsHf, whf, lane);
      GLWRITE(acc, bvF);
      __syncthreads();
      PkU pkf; float hvf[4];
      EPILOGUE(0, hvf, pkf);
      _Float16* houtF = P.hb + ((size_t)(t + 1) * 4 + 2) * SLAB + erow * Hh + cb + ec0;
      __hip_atomic_store((unsigned long long*)houtF, pkf.u, __ATOMIC_RELAXED, __HIP_MEMORY_SCOPE_AGENT);
      *(unsigned long long*)(P.allh + ((size_t)erow * Tt + t) * D2H + 0 * Hh + cb + ec0) = pkf.u;

      // ================= B segment (dir 1) =================
      if (tid < 32) {
        const unsigned* p = ownFb + tid * 16;
        while (__hip_atomic_load(p, __ATOMIC_RELAXED, __HIP_MEMORY_SCOPE_AGENT) < (unsigned)t)
          __builtin_amdgcn_s_sleep(1);
      } else if (tid < 64) {
        const unsigned* p = l1Fb + (tid - 32) * 16;
        while (__hip_atomic_load(p, __ATOMIC_RELAXED, __HIP_MEMORY_SCOPE_AGENT) < (unsigned)(t + 1))
          __builtin_amdgcn_s_sleep(1);
      }
      __syncthreads();
      stage64k((const char*)(P.hb + ((size_t)t * 4 + 3) * SLAB), (char*)ldsHb, tid);
      f32x4 acc2[4] = {};
      if (w != 3) {  // x-side: h1_b(t) direct from global
        const _Float16* xr = P.hb + ((size_t)(t + 1) * 4 + 1) * SLAB + (lane & 15) * Hh + 8 * (lane >> 4);
#pragma unroll
        for (int k = 0; k < 16; ++k)
#pragma unroll
          for (int mt = 0; mt < 4; ++mt)
            acc2[mt] = __builtin_amdgcn_mfma_f32_16x16x32_f16(
                *(const f16x8*)(xr + mt * 16 * Hh + k * 32), wxb[k], acc2[mt], 0, 0, 0);
      }
      asm volatile("s_waitcnt vmcnt(0)" ::: "memory");   // drains B stage/x + F epilogue stores
      __syncthreads();
      if (tid == 0)
        __hip_atomic_store(flagF, (unsigned)(t + 1), __ATOMIC_RELAXED, __HIP_MEMORY_SCOPE_AGENT);
      if (w != 2) hside(acc2, (const char*)ldsHb, whb, lane);
      GLWRITE(acc2, bvB);
      __syncthreads();
      PkU pkb; float hvb[4];
      EPILOGUE(1, hvb, pkb);
      _Float16* houtB = P.hb + ((size_t)(t + 1) * 4 + 3) * SLAB + erow * Hh + cb + ec0;
      __hip_atomic_store((unsigned long long*)houtB, pkb.u, __ATOMIC_RELAXED, __HIP_MEMORY_SCOPE_AGENT);
      *(unsigned long long*)(P.allh + ((size_t)erow * Tt + t) * D2H + 1 * Hh + cb + ec0) = pkb.u;
      asm volatile("s_waitcnt vmcnt(0)" ::: "memory");
      __syncthreads();
      if (tid == 0)
        __hip_atomic_store(flagB, (unsigned)(t + 1), __ATOMIC_RELAXED, __HIP_MEMORY_SCOPE_AGENT);
    }
  }
#undef GLWRITE
#undef EPILOGUE
}

// ---------------- tiled TN GEMM: C = [A|A2](MxK, K-major) * B(NxK, K-major)^T ----------------
struct TArgs {
  const _Float16* A; const _Float16* A2; const _Float16* B;
  _Float16* Ch; float* Cf;
  const float* bias;
  int lda, ldb, ldc, K, Ksplit;
  long long sAz, sBz, sCz;
};

template<int MODE>  // 0: f16 out; 1: f16 out + bias; 2: f32 out
__global__ __launch_bounds__(256) void gemm_tiled(TArgs g) {
  int z = blockIdx.z;
  const _Float16* A  = g.A + (size_t)z * g.sAz;
  const _Float16* Bm = g.B + (size_t)z * g.sBz;
  int m0 = blockIdx.y * 128, n0 = blockIdx.x * 128;
  int tid = threadIdx.x, lane = tid & 63;
  int wr = (tid >> 7) & 1, wc = (tid >> 6) & 1;  // wave grid 2x2

  __shared__ _Float16 sA[2][128 * 64];
  __shared__ _Float16 sB[2][128 * 64];

  int ldab = g.lda * 2, ldbb = g.ldb * 2;

#define STAGE(buf, kt)                                                                   \
  {                                                                                      \
    int k0 = (kt) * 64;                                                                  \
    const _Float16* Asrc = A; int ka = k0;                                               \
    if (k0 >= g.Ksplit) { Asrc = g.A2; ka = k0 - g.Ksplit; }                             \
    const char* ab = (const char*)(Asrc + (size_t)m0 * g.lda + ka);                      \
    const char* bb = (const char*)(Bm  + (size_t)n0 * g.ldb + k0);                       \
    char* la = (char*)sA[buf]; char* lb = (char*)sB[buf];                                \
    _Pragma("unroll")                                                                    \
    for (int it = 0; it < 4; ++it) {                                                     \
      int o = (it * 256 + tid) * 16;                                                     \
      int row = o >> 7, boff = o & 127;                                                  \
      int sw = boff ^ ((row & 7) << 4);                                                  \
      __builtin_amdgcn_global_load_lds((gas_t)(ab + (size_t)row * ldab + sw),            \
                                       (las_t)(la + o), 16, 0, 0);                       \
      __builtin_amdgcn_global_load_lds((gas_t)(bb + (size_t)row * ldbb + sw),            \
                                       (las_t)(lb + o), 16, 0, 0);                       \
    }                                                                                    \
  }

  f32x4 acc[4][4] = {};
  int nkt = g.K / 64;
  STAGE(0, 0);
  asm volatile("s_waitcnt vmcnt(0)" ::: "memory");
  __syncthreads();

  int cbyte = (lane >> 4) << 4;  // 0,16,32,48
  for (int kt = 0; kt < nkt; ++kt) {
    int buf = kt & 1;
    if (kt + 1 < nkt) STAGE(buf ^ 1, kt + 1);
    const char* la = (const char*)sA[buf];
    const char* lb = (const char*)sB[buf];
    f16x8 af[2][4], bfr[2][4];
#pragma unroll
    for (int kk = 0; kk < 2; ++kk) {
#pragma unroll
      for (int mt = 0; mt < 4; ++mt) {
        int r = wr * 64 + mt * 16 + (lane & 15);
        int c = kk * 64 + cbyte;
        af[kk][mt] = *(const f16x8*)(la + r * 128 + (c ^ ((r & 7) << 4)));
      }
#pragma unroll
      for (int nt = 0; nt < 4; ++nt) {
        int r = wc * 64 + nt * 16 + (lane & 15);
        int c = kk * 64 + cbyte;
        bfr[kk][nt] = *(const f16x8*)(lb + r * 128 + (c ^ ((r & 7) << 4)));
      }
    }
#pragma unroll
    for (int kk = 0; kk < 2; ++kk)
#pragma unroll
      for (int mt = 0; mt < 4; ++mt)
#pragma unroll
        for (int nt = 0; nt < 4; ++nt)
          acc[mt][nt] = __builtin_amdgcn_mfma_f32_16x16x32_f16(af[kk][mt], bfr[kk][nt], acc[mt][nt], 0, 0, 0);
    asm volatile("s_waitcnt vmcnt(0)" ::: "memory");
    __syncthreads();
  }
#undef STAGE

  int rb = 4 * (lane >> 4);
#pragma unroll
  for (int nt = 0; nt < 4; ++nt) {
    int col = n0 + wc * 64 + nt * 16 + (lane & 15);
    float bv = (MODE == 1) ? g.bias[col] : 0.0f;
#pragma unroll
    for (int mt = 0; mt < 4; ++mt) {
#pragma unroll
      for (int r = 0; r < 4; ++r) {
        int row = m0 + wr * 64 + mt * 16 + rb + r;
        size_t idx = (size_t)z * g.sCz + (size_t)row * g.ldc + col;
        float v = acc[mt][nt][r] + bv;
        if (MODE == 2) g.Cf[idx] = v; else g.Ch[idx] = (_Float16)v;
      }
    }
  }
}

// ---------------- row softmax: scores f32 (.,512) -> p f16 ----------------
__global__ __launch_bounds__(256) void softmax_rows(const float* __restrict__ sc, _Float16* __restrict__ p) {
  int row = blockIdx.x * 4 + (threadIdx.x >> 6);
  int lane = threadIdx.x & 63;
  const float* s = sc + (size_t)row * 512 + lane * 8;
  float v[8];
  float4 q0 = *(const float4*)s, q1 = *(const float4*)(s + 4);
  v[0]=q0.x; v[1]=q0.y; v[2]=q0.z; v[3]=q0.w; v[4]=q1.x; v[5]=q1.y; v[6]=q1.z; v[7]=q1.w;
  float mx = v[0];
#pragma unroll
  for (int j = 1; j < 8; ++j) mx = fmaxf(mx, v[j]);
  for (int o = 32; o; o >>= 1) mx = fmaxf(mx, __shfl_xor(mx, o));
  float sum = 0.f;
#pragma unroll
  for (int j = 0; j < 8; ++j) { v[j] = expf(v[j] - mx); sum += v[j]; }
  for (int o = 32; o; o >>= 1) sum += __shfl_xor(sum, o);
  float inv = 1.0f / sum;
  _Float16* pd = p + (size_t)row * 512 + lane * 8;
#pragma unroll
  for (int j = 0; j < 8; ++j) pd[j] = (_Float16)(v[j] * inv);
}

// ---------------- per-batch transpose: allhT[b][d][t] = allh[b][t][d] ----------------
__global__ void transpose_bt(const _Float16* __restrict__ allh, _Float16* __restrict__ allhT) {
  __shared__ _Float16 tile[32][33];
  int b = blockIdx.z;
  int d0 = blockIdx.x * 32, t0 = blockIdx.y * 32;
  int tx = threadIdx.x, ty = threadIdx.y;  // (32, 8)
  const _Float16* in = allh + (size_t)b * Tt * D2H;
  _Float16* outp = allhT + (size_t)b * D2H * Tt;
#pragma unroll
  for (int j = 0; j < 4; ++j)
    tile[ty + 8 * j][tx] = in[(size_t)(t0 + ty + 8 * j) * D2H + d0 + tx];
  __syncthreads();
#pragma unroll
  for (int j = 0; j < 4; ++j)
    outp[(size_t)(d0 + ty + 8 * j) * Tt + t0 + tx] = tile[tx][ty + 8 * j];
}

// ---------------- gating epilogue: attn = g*f + (1-g)*allh ----------------
__global__ __launch_bounds__(256) void gating(const _Float16* __restrict__ gfpre,
                                              const _Float16* __restrict__ allh,
                                              const float* __restrict__ bg,
                                              const float* __restrict__ bfv,
                                              float* __restrict__ out_attn) {
  int i = blockIdx.x * 256 + threadIdx.x;   // over (B*T) * 128 groups
  int m = i >> 7, c0 = (i & 127) << 3;
  f16x8 gv = *(const f16x8*)(gfpre + (size_t)m * 2048 + c0);
  f16x8 fv = *(const f16x8*)(gfpre + (size_t)m * 2048 + 1024 + c0);
  f16x8 ah = *(const f16x8*)(allh + (size_t)m * D2H + c0);
  float res[8];
#pragma unroll
  for (int j = 0; j < 8; ++j) {
    float gg = sigm((float)gv[j] + bg[c0 + j]);
    float ff = tanhf((float)fv[j] + bfv[c0 + j]);
    res[j] = gg * ff + (1.0f - gg) * (float)ah[j];
  }
  float4* dst = (float4*)(out_attn + (size_t)m * D2H + c0);
  dst[0] = make_float4(res[0], res[1], res[2], res[3]);
  dst[1] = make_float4(res[4], res[5], res[6], res[7]);
}

// ---------------- final concat output ----------------
__global__ void write_concat(const float* __restrict__ h1fin, float* __restrict__ out) {
  int i = blockIdx.x * 256 + threadIdx.x;
  if (i >= Bb * D2H) return;
  int b = i >> 10, c = i & 1023;
  out[i] = (c < Hh) ? h1fin[(size_t)b * Hh + c] : h1fin[(size_t)(Bb + b) * Hh + (c - Hh)];
}

// =============================== host ===============================
extern "C" void kernel_launch(void* const* d_in, const int* in_sizes, int n_in,
                              void* d_out, int out_size, void* d_ws, size_t ws_size,
                              hipStream_t stream) {
  const int*   context = (const int*)d_in[0];
  const int*   tags    = (const int*)d_in[1];
  const float* glove   = (const float*)d_in[2];
  const float* bio     = (const float*)d_in[3];
  const float* b_lin   = (const float*)d_in[21];
  const float* b_g     = (const float*)d_in[23];
  const float* b_f     = (const float*)d_in[25];

  char* ws = (char*)d_ws;
  size_t off = 0;
  auto carve = [&](size_t bytes) -> void* {
    void* pp = ws + off;
    off = (off + bytes + 255) & ~(size_t)255;
    return pp;
  };

  _Float16* xt = (_Float16*)carve((size_t)Tt * Bb * INPP * 2);
  _Float16 *Wx16[2][2], *Wh16[2][2];
  Wx16[0][0] = (_Float16*)carve((size_t)1536 * 320 * 2);
  Wx16[1][0] = (_Float16*)carve((size_t)1536 * 320 * 2);
  Wx16[0][1] = (_Float16*)carve((size_t)1536 * 512 * 2);
  Wx16[1][1] = (_Float16*)carve((size_t)1536 * 512 * 2);
  for (int d = 0; d < 2; ++d)
    for (int l = 0; l < 2; ++l) Wh16[d][l] = (_Float16*)carve((size_t)1536 * 512 * 2);
  _Float16* wlin = (_Float16*)carve((size_t)1024 * 1024 * 2);
  _Float16* wgf  = (_Float16*)carve((size_t)2048 * 2048 * 2);
  _Float16* allh  = (_Float16*)carve((size_t)Bb * Tt * D2H * 2);      // 64 MiB
  _Float16* allhT = (_Float16*)carve((size_t)Bb * Tt * D2H * 2);      // 64 MiB (hb / gf_pre alias)
  float*    scores = (float*)carve((size_t)Bb * Tt * Tt * 4);          // 64 MiB (hb / gf_pre alias)
  _Float16* pmat   = (_Float16*)carve((size_t)Bb * Tt * Tt * 2);       // 32 MiB (hb tail alias)
  _Float16* qctx   = (_Float16*)carve((size_t)Bb * Tt * D2H * 2);      // q, then ctx
  float*    h1fin  = (float*)carve((size_t)2 * Bb * Hh * 4);
  unsigned* flags  = (unsigned*)carve((size_t)4 * 32 * 16 * 4);        // 8KB

  // hb: (Tt+1)*4*SLAB*2 = 128.25 MiB, aliases allhT+scores+pmat-head (dead during recurrence)
  _Float16* hb = allhT;
  // gf_pre: 32768 x 2048 f16 = 128 MiB, aliases allhT+scores exactly (dead by gf time)
  _Float16* gfpre = allhT;

  hipMemsetAsync(hb, 0, (size_t)4 * SLAB * 2, stream);          // slab t=0 (4 units) = 0
  hipMemsetAsync(flags, 0, (size_t)4 * 32 * 16 * 4, stream);    // progress flags

  auto conv = [&](const void* src, _Float16* dst, int rows, int csrc, int cdst) {
    int total = rows * cdst;
    convert_pad<<<(total + 255) / 256, 256, 0, stream>>>((const float*)src, dst, rows, csrc, cdst);
  };
  conv(d_in[4],  Wx16[0][0], 1536, 303, 320);
  conv(d_in[12], Wx16[1][0], 1536, 303, 320);
  conv(d_in[8],  Wx16[0][1], 1536, 512, 512);
  conv(d_in[16], Wx16[1][1], 1536, 512, 512);
  conv(d_in[5],  Wh16[0][0], 1536, 512, 512);
  conv(d_in[13], Wh16[1][0], 1536, 512, 512);
  conv(d_in[9],  Wh16[0][1], 1536, 512, 512);
  conv(d_in[17], Wh16[1][1], 1536, 512, 512);
  conv(d_in[20], wlin, 1024, 1024, 1024);
  conv(d_in[22], wgf, 1024, 2048, 2048);
  conv(d_in[24], wgf + (size_t)1024 * 2048, 1024, 2048, 2048);

  embed_kernel<<<Tt * Bb, 64, 0, stream>>>(context, tags, glove, bio, xt);

  GruParams GP;
  GP.xt = xt;
  // unit = layer*2 + dir
  GP.Wx[0] = Wx16[0][0]; GP.Wx[1] = Wx16[1][0]; GP.Wx[2] = Wx16[0][1]; GP.Wx[3] = Wx16[1][1];
  GP.Wh[0] = Wh16[0][0]; GP.Wh[1] = Wh16[1][0]; GP.Wh[2] = Wh16[0][1]; GP.Wh[3] = Wh16[1][1];
  GP.bih[0] = (const float*)d_in[6];  GP.bhh[0] = (const float*)d_in[7];
  GP.bih[1] = (const float*)d_in[14]; GP.bhh[1] = (const float*)d_in[15];
  GP.bih[2] = (const float*)d_in[10]; GP.bhh[2] = (const float*)d_in[11];
  GP.bih[3] = (const float*)d_in[18]; GP.bhh[3] = (const float*)d_in[19];
  GP.hb = hb;
  GP.allh = allh;
  GP.h1fin = h1fin;

  gru_persist<<<64, 256, 0, stream>>>(GP, flags);

  TArgs ga;
  // q = all_h @ W_lin^T + b_lin -> f16 qctx
  ga.A = allh; ga.A2 = allh; ga.B = wlin;
  ga.Ch = qctx; ga.Cf = nullptr; ga.bias = b_lin;
  ga.lda = 1024; ga.ldb = 1024; ga.ldc = 1024; ga.K = 1024; ga.Ksplit = 1 << 30;
  ga.sAz = 0; ga.sBz = 0; ga.sCz = 0;
  gemm_tiled<1><<<dim3(8, 256, 1), 256, 0, stream>>>(ga);

  // scores[b] = q[b] @ all_h[b]^T -> f32
  ga.A = qctx; ga.A2 = qctx; ga.B = allh;
  ga.Ch = nullptr; ga.Cf = scores; ga.bias = nullptr;
  ga.lda = 1024; ga.ldb = 1024; ga.ldc = 512; ga.K = 1024; ga.Ksplit = 1 << 30;
  ga.sAz = (long long)512 * 1024; ga.sBz = (long long)512 * 1024; ga.sCz = (long long)512 * 512;
  gemm_tiled<2><<<dim3(4, 4, 64), 256, 0, stream>>>(ga);

  softmax_rows<<<(Bb * Tt) / 4, 256, 0, stream>>>(scores, pmat);

  transpose_bt<<<dim3(32, 16, 64), dim3(32, 8), 0, stream>>>(allh, allhT);

  // ctx[b] = p[b] @ (all_hT[b])^T -> f16 (overwrites q in qctx)
  ga.A = pmat; ga.A2 = pmat; ga.B = allhT;
  ga.Ch = qctx; ga.Cf = nullptr; ga.bias = nullptr;
  ga.lda = 512; ga.ldb = 512; ga.ldc = 1024; ga.K = 512; ga.Ksplit = 1 << 30;
  ga.sAz = (long long)512 * 512; ga.sBz = (long long)1024 * 512; ga.sCz = (long long)512 * 1024;
  gemm_tiled<0><<<dim3(8, 4, 64), 256, 0, stream>>>(ga);

  // gf_pre = [ctx | all_h] @ Wgf^T -> f16 (overwrites allhT+scores region)
  ga.A = qctx; ga.A2 = allh; ga.B = wgf;
  ga.Ch = gfpre; ga.Cf = nullptr; ga.bias = nullptr;
  ga.lda = 1024; ga.ldb = 2048; ga.ldc = 2048; ga.K = 2048; ga.Ksplit = 1024;
  ga.sAz = 0; ga.sBz = 0; ga.sCz = 0;
  gemm_tiled<0><<<dim3(16, 256, 1), 256, 0, stream>>>(ga);

  float* out_attn = (float*)d_out + (size_t)Bb * D2H;
  gating<<<(Bb * Tt * 128) / 256, 256, 0, stream>>>(gfpre, allh, b_g, b_f, out_attn);

  write_concat<<<(Bb * D2H + 255) / 256, 256, 0, stream>>>(h1fin, (float*)d_out);
}

// Round 8
// 8380.928 us; speedup vs baseline: 1.5267x; 1.5267x over previous
//
#include <hip/hip_runtime.h>
#include <hip/hip_bf16.h>
#include <math.h>

typedef _Float16 f16x8 __attribute__((ext_vector_type(8)));
typedef float    f32x4 __attribute__((ext_vector_type(4)));

#define DEV __device__ __forceinline__

static constexpr int Ee   = 300;   // glove dim
static constexpr int INP  = 303;   // E + 3
static constexpr int INPP = 320;   // padded input dim
static constexpr int Hh   = 512;
static constexpr int Bb   = 64;
static constexpr int Tt   = 512;
static constexpr int D2H  = 1024;  // 2H
static constexpr int SLAB = Bb * Hh;  // one h-state slab (elements)

typedef const void __attribute__((address_space(1)))* gas_t;
typedef void __attribute__((address_space(3)))* las_t;

// ---- MFMA fragment load: K-major matrix M[row][k], frag[l][j] = M[row0+(l&15)][k0+8*(l>>4)+j]
DEV f16x8 ldfrag(const _Float16* base, int ld, int row0, int k0, int lane) {
  return *reinterpret_cast<const f16x8*>(base + (size_t)(row0 + (lane & 15)) * ld + (k0 + 8 * (lane >> 4)));
}
DEV float sigm(float x) { return 1.0f / (1.0f + expf(-x)); }

DEV void pollwait(const unsigned* p, unsigned tgt) {
  while (__hip_atomic_load(p, __ATOMIC_RELAXED, __HIP_MEMORY_SCOPE_AGENT) < tgt)
    __builtin_amdgcn_s_sleep(1);
}

// ---------------- weight convert (f32 -> f16, optional column pad) ----------------
__global__ void convert_pad(const float* __restrict__ src, _Float16* __restrict__ dst,
                            int rows, int csrc, int cdst) {
  int i = blockIdx.x * 256 + threadIdx.x;
  if (i >= rows * cdst) return;
  int r = i / cdst, c = i - r * cdst;
  dst[i] = (c < csrc) ? (_Float16)src[(size_t)r * csrc + c] : (_Float16)0.0f;
}

// ---------------- embedding: xt (T, B, INPP) f16 ----------------
__global__ void embed_kernel(const int* __restrict__ context, const int* __restrict__ tags,
                             const float* __restrict__ glove, const float* __restrict__ bio,
                             _Float16* __restrict__ xt) {
  int blk = blockIdx.x;            // t*64 + b
  int t = blk >> 6, b = blk & 63;
  int cid = context[b * Tt + t];   // context (B,T,1)
  int tag = tags[b * Tt + t];      // (B,T)
  _Float16* dst = xt + (size_t)blk * INPP;
  for (int c = threadIdx.x; c < INPP; c += 64) {
    float v = (c < Ee) ? glove[(size_t)cid * Ee + c]
                       : ((c < INP) ? bio[tag * 3 + (c - Ee)] : 0.0f);
    dst[c] = (_Float16)v;
  }
}

// ---------------- persistent GRU recurrence (round-5 protocol, direct operand reads) ----------------
// unit = layer*2 + dir. hb slabs: hb + ((size_t)t*4 + unit)*SLAB holds h_{t-1}
// (slab t=0 zeros). Step t reads slab t, write-through publishes slab t+1.
struct GruParams {
  const _Float16* xt;
  const _Float16* Wx[4];   // input-side weights (ld = 320 for L1, 512 for L2)
  const _Float16* Wh[4];   // hidden-side weights (ld = 512)
  const float* bih[4];
  const float* bhh[4];
  _Float16* hb;            // fresh h16 slabs, (Tt+1) x 4 x SLAB
  _Float16* allh;          // (B, T, 2H) f16
  float*    h1fin;         // [dir][64][512] fp32 layer-1 final states
};

// acc += A(64x512 global, ld=512) * W^T, A-fragments read DIRECT from global (LLC);
// per-wave load pipeline, no block-wide drain. Same pattern as round-5 L2 x-side (proven).
DEV void gdir(f32x4* acc, const _Float16* __restrict__ Abase, const f16x8* wreg, int lane) {
  const _Float16* ar = Abase + (size_t)(lane & 15) * Hh + 8 * (lane >> 4);
#pragma unroll
  for (int k = 0; k < 16; ++k) {
    f16x8 af[4];
#pragma unroll
    for (int mt = 0; mt < 4; ++mt) af[mt] = *(const f16x8*)(ar + (size_t)mt * 16 * Hh + k * 32);
#pragma unroll
    for (int mt = 0; mt < 4; ++mt)
      acc[mt] = __builtin_amdgcn_mfma_f32_16x16x32_f16(af[mt], wreg[k], acc[mt], 0, 0, 0);
  }
}

__global__ __launch_bounds__(256, 1) void gru_persist(GruParams P, unsigned* flags) {
  int unit = blockIdx.x >> 5;         // layer*2 + dir
  int blk  = blockIdx.x & 31;
  int cb   = blk << 4;                // h-column base
  int layer = unit >> 1, dir = unit & 1;
  unsigned* myFlag = flags + ((size_t)unit * 32 + blk) * 16;  // 64B/flag
  const unsigned* ownF = flags + (size_t)unit * 32 * 16;
  const unsigned* l1F  = flags + (size_t)dir  * 32 * 16;      // L1 unit of same dir

  int tid = threadIdx.x, w = tid >> 6, lane = tid & 63;
  // wave roles: 0 -> r, 1 -> z, 2 -> n_i (x-side only), 3 -> n_h (h-side only)
  int nrow = ((w == 0) ? 0 : (w == 1) ? Hh : 2 * Hh) + cb;

  const _Float16* Wx = P.Wx[unit];
  const _Float16* Wh = P.Wh[unit];
  const float* bih = P.bih[unit];
  const float* bhh = P.bhh[unit];

  int col = lane & 15;
  float bv;
  if      (w == 0) bv = bih[cb + col] + bhh[cb + col];
  else if (w == 1) bv = bih[Hh + cb + col] + bhh[Hh + cb + col];
  else if (w == 2) bv = bih[2 * Hh + cb + col];
  else             bv = bhh[2 * Hh + cb + col];

  __shared__ float gl[4][64][20];     // gate pre-activations (stride 20)
  __shared__ float h32s[64][17];      // block-private fp32 h state
  for (int e = tid; e < 64 * 17; e += 256) ((float*)h32s)[e] = 0.0f;
  __syncthreads();

  int rbase = 4 * (lane >> 4);
  int erow = tid >> 2, ec0 = (tid & 3) << 2;  // epilogue: 4 cols/thread

#define GLWRITE(ACC)                                          \
  _Pragma("unroll")                                           \
  for (int mt = 0; mt < 4; ++mt)                              \
    _Pragma("unroll")                                         \
    for (int r = 0; r < 4; ++r)                               \
      gl[w][mt * 16 + rbase + r][col] = (ACC)[mt][r] + bv;

  union PkU { _Float16 h[4]; unsigned long long u; };

  if (layer == 0) {
    // ---- preload weights into registers ----
    f16x8 wxr[10], whr[16];
    if (w != 3) {
#pragma unroll
      for (int k = 0; k < 10; ++k) wxr[k] = ldfrag(Wx, INPP, nrow, k * 32, lane);
    }
    if (w != 2) {
#pragma unroll
      for (int k = 0; k < 16; ++k) whr[k] = ldfrag(Wh, Hh, nrow, k * 32, lane);
    }
    for (int t = 0; t < Tt; ++t) {
      f32x4 acc[4] = {};
      // x-side first: independent of the barrier, overlaps poll latency
      if (w != 3) {
        int tt = dir ? (Tt - 1 - t) : t;
        const _Float16* arow = P.xt + (size_t)tt * Bb * INPP + (lane & 15) * INPP + 8 * (lane >> 4);
#pragma unroll
        for (int k = 0; k < 10; ++k)
#pragma unroll
          for (int mt = 0; mt < 4; ++mt)
            acc[mt] = __builtin_amdgcn_mfma_f32_16x16x32_f16(
                *(const f16x8*)(arow + mt * 16 * INPP + k * 32), wxr[k], acc[mt], 0, 0, 0);
      }
      // wait: all 32 sibling blocks published step t-1
      if (tid < 32) pollwait(ownF + tid * 16, (unsigned)t);
      __syncthreads();
      // h-side: A-fragments direct from the fresh slab (per-wave pipelined loads)
      if (w != 2) gdir(acc, P.hb + ((size_t)t * 4 + unit) * SLAB, whr, lane);
      GLWRITE(acc);
      __syncthreads();

      PkU pk; float hv[4];
#pragma unroll
      for (int j = 0; j < 4; ++j) {
        int c = ec0 + j;
        float rr = sigm(gl[0][erow][c]);
        float zz = sigm(gl[1][erow][c]);
        float nn = tanhf(gl[2][erow][c] + rr * gl[3][erow][c]);
        float hp = h32s[erow][c];
        hv[j] = (1.0f - zz) * nn + zz * hp;
        h32s[erow][c] = hv[j];
        pk.h[j] = (_Float16)hv[j];
      }
      _Float16* hout = P.hb + ((size_t)(t + 1) * 4 + unit) * SLAB + erow * Hh + cb + ec0;
      __hip_atomic_store((unsigned long long*)hout, pk.u, __ATOMIC_RELAXED, __HIP_MEMORY_SCOPE_AGENT);
      if (t == Tt - 1)
        *(float4*)(P.h1fin + ((size_t)dir * Bb + erow) * Hh + cb + ec0) = make_float4(hv[0], hv[1], hv[2], hv[3]);

      asm volatile("s_waitcnt vmcnt(0)" ::: "memory");   // publish drained to coherence point
      __syncthreads();
      if (tid == 0)
        __hip_atomic_store(myFlag, (unsigned)(t + 1), __ATOMIC_RELAXED, __HIP_MEMORY_SCOPE_AGENT);
    }
  } else {
    f16x8 wxr[16], whr[16];
    if (w != 3) {
#pragma unroll
      for (int k = 0; k < 16; ++k) wxr[k] = ldfrag(Wx, Hh, nrow, k * 32, lane);
    }
    if (w != 2) {
#pragma unroll
      for (int k = 0; k < 16; ++k) whr[k] = ldfrag(Wh, Hh, nrow, k * 32, lane);
    }
    for (int t = 0; t < Tt; ++t) {
      // wait: own siblings >= t AND producing L1 unit >= t+1 (h1(t) complete)
      if (tid < 64) {
        const unsigned* p = (tid < 32) ? (ownF + tid * 16) : (l1F + (tid - 32) * 16);
        unsigned tg = (tid < 32) ? (unsigned)t : (unsigned)(t + 1);
        pollwait(p, tg);
      }
      __syncthreads();

      f32x4 acc[4] = {};
      if (w != 3)  // x-side: h1(t) direct from fresh slab
        gdir(acc, P.hb + ((size_t)(t + 1) * 4 + dir) * SLAB, wxr, lane);
      if (w != 2)  // h-side: own hprev direct from fresh slab
        gdir(acc, P.hb + ((size_t)t * 4 + unit) * SLAB, whr, lane);
      GLWRITE(acc);
      __syncthreads();

      PkU pk; float hv[4];
#pragma unroll
      for (int j = 0; j < 4; ++j) {
        int c = ec0 + j;
        float rr = sigm(gl[0][erow][c]);
        float zz = sigm(gl[1][erow][c]);
        float nn = tanhf(gl[2][erow][c] + rr * gl[3][erow][c]);
        float hp = h32s[erow][c];
        hv[j] = (1.0f - zz) * nn + zz * hp;
        h32s[erow][c] = hv[j];
        pk.h[j] = (_Float16)hv[j];
      }
      _Float16* hout = P.hb + ((size_t)(t + 1) * 4 + unit) * SLAB + erow * Hh + cb + ec0;
      __hip_atomic_store((unsigned long long*)hout, pk.u, __ATOMIC_RELAXED, __HIP_MEMORY_SCOPE_AGENT);

      asm volatile("s_waitcnt vmcnt(0)" ::: "memory");
      __syncthreads();
      if (tid == 0)
        __hip_atomic_store(myFlag, (unsigned)(t + 1), __ATOMIC_RELAXED, __HIP_MEMORY_SCOPE_AGENT);
      // allh publication off the critical publish path (consumed post-kernel)
      *(unsigned long long*)(P.allh + ((size_t)erow * Tt + t) * D2H + dir * Hh + cb + ec0) = pk.u;
    }
  }
#undef GLWRITE
}

// ---------------- tiled TN GEMM: C = [A|A2](MxK, K-major) * B(NxK, K-major)^T ----------------
struct TArgs {
  const _Float16* A; const _Float16* A2; const _Float16* B;
  _Float16* Ch; float* Cf;
  const float* bias;
  int lda, ldb, ldc, K, Ksplit;
  long long sAz, sBz, sCz;
};

template<int MODE>  // 0: f16 out; 1: f16 out + bias; 2: f32 out
__global__ __launch_bounds__(256) void gemm_tiled(TArgs g) {
  int z = blockIdx.z;
  const _Float16* A  = g.A + (size_t)z * g.sAz;
  const _Float16* Bm = g.B + (size_t)z * g.sBz;
  int m0 = blockIdx.y * 128, n0 = blockIdx.x * 128;
  int tid = threadIdx.x, lane = tid & 63;
  int wr = (tid >> 7) & 1, wc = (tid >> 6) & 1;  // wave grid 2x2

  __shared__ _Float16 sA[2][128 * 64];
  __shared__ _Float16 sB[2][128 * 64];

  int ldab = g.lda * 2, ldbb = g.ldb * 2;

#define STAGE(buf, kt)                                                                   \
  {                                                                                      \
    int k0 = (kt) * 64;                                                                  \
    const _Float16* Asrc = A; int ka = k0;                                               \
    if (k0 >= g.Ksplit) { Asrc = g.A2; ka = k0 - g.Ksplit; }                             \
    const char* ab = (const char*)(Asrc + (size_t)m0 * g.lda + ka);                      \
    const char* bb = (const char*)(Bm  + (size_t)n0 * g.ldb + k0);                       \
    char* la = (char*)sA[buf]; char* lb = (char*)sB[buf];                                \
    _Pragma("unroll")                                                                    \
    for (int it = 0; it < 4; ++it) {                                                     \
      int o = (it * 256 + tid) * 16;                                                     \
      int row = o >> 7, boff = o & 127;                                                  \
      int sw = boff ^ ((row & 7) << 4);                                                  \
      __builtin_amdgcn_global_load_lds((gas_t)(ab + (size_t)row * ldab + sw),            \
                                       (las_t)(la + o), 16, 0, 0);                       \
      __builtin_amdgcn_global_load_lds((gas_t)(bb + (size_t)row * ldbb + sw),            \
                                       (las_t)(lb + o), 16, 0, 0);                       \
    }                                                                                    \
  }

  f32x4 acc[4][4] = {};
  int nkt = g.K / 64;
  STAGE(0, 0);
  asm volatile("s_waitcnt vmcnt(0)" ::: "memory");
  __syncthreads();

  int cbyte = (lane >> 4) << 4;  // 0,16,32,48
  for (int kt = 0; kt < nkt; ++kt) {
    int buf = kt & 1;
    if (kt + 1 < nkt) STAGE(buf ^ 1, kt + 1);
    const char* la = (const char*)sA[buf];
    const char* lb = (const char*)sB[buf];
    f16x8 af[2][4], bfr[2][4];
#pragma unroll
    for (int kk = 0; kk < 2; ++kk) {
#pragma unroll
      for (int mt = 0; mt < 4; ++mt) {
        int r = wr * 64 + mt * 16 + (lane & 15);
        int c = kk * 64 + cbyte;
        af[kk][mt] = *(const f16x8*)(la + r * 128 + (c ^ ((r & 7) << 4)));
      }
#pragma unroll
      for (int nt = 0; nt < 4; ++nt) {
        int r = wc * 64 + nt * 16 + (lane & 15);
        int c = kk * 64 + cbyte;
        bfr[kk][nt] = *(const f16x8*)(lb + r * 128 + (c ^ ((r & 7) << 4)));
      }
    }
#pragma unroll
    for (int kk = 0; kk < 2; ++kk)
#pragma unroll
      for (int mt = 0; mt < 4; ++mt)
#pragma unroll
        for (int nt = 0; nt < 4; ++nt)
          acc[mt][nt] = __builtin_amdgcn_mfma_f32_16x16x32_f16(af[kk][mt], bfr[kk][nt], acc[mt][nt], 0, 0, 0);
    asm volatile("s_waitcnt vmcnt(0)" ::: "memory");
    __syncthreads();
  }
#undef STAGE

  int rb = 4 * (lane >> 4);
#pragma unroll
  for (int nt = 0; nt < 4; ++nt) {
    int col = n0 + wc * 64 + nt * 16 + (lane & 15);
    float bv = (MODE == 1) ? g.bias[col] : 0.0f;
#pragma unroll
    for (int mt = 0; mt < 4; ++mt) {
#pragma unroll
      for (int r = 0; r < 4; ++r) {
        int row = m0 + wr * 64 + mt * 16 + rb + r;
        size_t idx = (size_t)z * g.sCz + (size_t)row * g.ldc + col;
        float v = acc[mt][nt][r] + bv;
        if (MODE == 2) g.Cf[idx] = v; else g.Ch[idx] = (_Float16)v;
      }
    }
  }
}

// ---------------- row softmax: scores f32 (.,512) -> p f16 ----------------
__global__ __launch_bounds__(256) void softmax_rows(const float* __restrict__ sc, _Float16* __restrict__ p) {
  int row = blockIdx.x * 4 + (threadIdx.x >> 6);
  int lane = threadIdx.x & 63;
  const float* s = sc + (size_t)row * 512 + lane * 8;
  float v[8];
  float4 q0 = *(const float4*)s, q1 = *(const float4*)(s + 4);
  v[0]=q0.x; v[1]=q0.y; v[2]=q0.z; v[3]=q0.w; v[4]=q1.x; v[5]=q1.y; v[6]=q1.z; v[7]=q1.w;
  float mx = v[0];
#pragma unroll
  for (int j = 1; j < 8; ++j) mx = fmaxf(mx, v[j]);
  for (int o = 32; o; o >>= 1) mx = fmaxf(mx, __shfl_xor(mx, o));
  float sum = 0.f;
#pragma unroll
  for (int j = 0; j < 8; ++j) { v[j] = expf(v[j] - mx); sum += v[j]; }
  for (int o = 32; o; o >>= 1) sum += __shfl_xor(sum, o);
  float inv = 1.0f / sum;
  _Float16* pd = p + (size_t)row * 512 + lane * 8;
#pragma unroll
  for (int j = 0; j < 8; ++j) pd[j] = (_Float16)(v[j] * inv);
}

// ---------------- per-batch transpose: allhT[b][d][t] = allh[b][t][d] ----------------
__global__ void transpose_bt(const _Float16* __restrict__ allh, _Float16* __restrict__ allhT) {
  __shared__ _Float16 tile[32][33];
  int b = blockIdx.z;
  int d0 = blockIdx.x * 32, t0 = blockIdx.y * 32;
  int tx = threadIdx.x, ty = threadIdx.y;  // (32, 8)
  const _Float16* in = allh + (size_t)b * Tt * D2H;
  _Float16* outp = allhT + (size_t)b * D2H * Tt;
#pragma unroll
  for (int j = 0; j < 4; ++j)
    tile[ty + 8 * j][tx] = in[(size_t)(t0 + ty + 8 * j) * D2H + d0 + tx];
  __syncthreads();
#pragma unroll
  for (int j = 0; j < 4; ++j)
    outp[(size_t)(d0 + ty + 8 * j) * Tt + t0 + tx] = tile[tx][ty + 8 * j];
}

// ---------------- gating epilogue: attn = g*f + (1-g)*allh ----------------
__global__ __launch_bounds__(256) void gating(const _Float16* __restrict__ gfpre,
                                              const _Float16* __restrict__ allh,
                                              const float* __restrict__ bg,
                                              const float* __restrict__ bfv,
                                              float* __restrict__ out_attn) {
  int i = blockIdx.x * 256 + threadIdx.x;   // over (B*T) * 128 groups
  int m = i >> 7, c0 = (i & 127) << 3;
  f16x8 gv = *(const f16x8*)(gfpre + (size_t)m * 2048 + c0);
  f16x8 fv = *(const f16x8*)(gfpre + (size_t)m * 2048 + 1024 + c0);
  f16x8 ah = *(const f16x8*)(allh + (size_t)m * D2H + c0);
  float res[8];
#pragma unroll
  for (int j = 0; j < 8; ++j) {
    float gg = sigm((float)gv[j] + bg[c0 + j]);
    float ff = tanhf((float)fv[j] + bfv[c0 + j]);
    res[j] = gg * ff + (1.0f - gg) * (float)ah[j];
  }
  float4* dst = (float4*)(out_attn + (size_t)m * D2H + c0);
  dst[0] = make_float4(res[0], res[1], res[2], res[3]);
  dst[1] = make_float4(res[4], res[5], res[6], res[7]);
}

// ---------------- final concat output ----------------
__global__ void write_concat(const float* __restrict__ h1fin, float* __restrict__ out) {
  int i = blockIdx.x * 256 + threadIdx.x;
  if (i >= Bb * D2H) return;
  int b = i >> 10, c = i & 1023;
  out[i] = (c < Hh) ? h1fin[(size_t)b * Hh + c] : h1fin[(size_t)(Bb + b) * Hh + (c - Hh)];
}

// =============================== host ===============================
extern "C" void kernel_launch(void* const* d_in, const int* in_sizes, int n_in,
                              void* d_out, int out_size, void* d_ws, size_t ws_size,
                              hipStream_t stream) {
  const int*   context = (const int*)d_in[0];
  const int*   tags    = (const int*)d_in[1];
  const float* glove   = (const float*)d_in[2];
  const float* bio     = (const float*)d_in[3];
  const float* b_lin   = (const float*)d_in[21];
  const float* b_g     = (const float*)d_in[23];
  const float* b_f     = (const float*)d_in[25];

  char* ws = (char*)d_ws;
  size_t off = 0;
  auto carve = [&](size_t bytes) -> void* {
    void* pp = ws + off;
    off = (off + bytes + 255) & ~(size_t)255;
    return pp;
  };

  _Float16* xt = (_Float16*)carve((size_t)Tt * Bb * INPP * 2);
  _Float16 *Wx16[2][2], *Wh16[2][2];
  Wx16[0][0] = (_Float16*)carve((size_t)1536 * 320 * 2);
  Wx16[1][0] = (_Float16*)carve((size_t)1536 * 320 * 2);
  Wx16[0][1] = (_Float16*)carve((size_t)1536 * 512 * 2);
  Wx16[1][1] = (_Float16*)carve((size_t)1536 * 512 * 2);
  for (int d = 0; d < 2; ++d)
    for (int l = 0; l < 2; ++l) Wh16[d][l] = (_Float16*)carve((size_t)1536 * 512 * 2);
  _Float16* wlin = (_Float16*)carve((size_t)1024 * 1024 * 2);
  _Float16* wgf  = (_Float16*)carve((size_t)2048 * 2048 * 2);
  _Float16* allh  = (_Float16*)carve((size_t)Bb * Tt * D2H * 2);      // 64 MiB
  _Float16* allhT = (_Float16*)carve((size_t)Bb * Tt * D2H * 2);      // 64 MiB (hb / gf_pre alias)
  float*    scores = (float*)carve((size_t)Bb * Tt * Tt * 4);          // 64 MiB (hb / gf_pre alias)
  _Float16* pmat   = (_Float16*)carve((size_t)Bb * Tt * Tt * 2);       // 32 MiB (hb tail alias)
  _Float16* qctx   = (_Float16*)carve((size_t)Bb * Tt * D2H * 2);      // q, then ctx
  float*    h1fin  = (float*)carve((size_t)2 * Bb * Hh * 4);
  unsigned* flags  = (unsigned*)carve((size_t)4 * 32 * 16 * 4);        // 8KB, 64B per block-flag

  // hb: (Tt+1)*4*SLAB*2 = 128.25 MiB, aliases allhT+scores+pmat-head (dead during recurrence)
  _Float16* hb = allhT;
  // gf_pre: 32768 x 2048 f16 = 128 MiB, aliases allhT+scores (dead by gf time)
  _Float16* gfpre = allhT;

  hipMemsetAsync(hb, 0, (size_t)4 * SLAB * 2, stream);          // slab t=0 (4 units) = 0
  hipMemsetAsync(flags, 0, (size_t)4 * 32 * 16 * 4, stream);    // progress flags

  auto conv = [&](const void* src, _Float16* dst, int rows, int csrc, int cdst) {
    int total = rows * cdst;
    convert_pad<<<(total + 255) / 256, 256, 0, stream>>>((const float*)src, dst, rows, csrc, cdst);
  };
  conv(d_in[4],  Wx16[0][0], 1536, 303, 320);
  conv(d_in[12], Wx16[1][0], 1536, 303, 320);
  conv(d_in[8],  Wx16[0][1], 1536, 512, 512);
  conv(d_in[16], Wx16[1][1], 1536, 512, 512);
  conv(d_in[5],  Wh16[0][0], 1536, 512, 512);
  conv(d_in[13], Wh16[1][0], 1536, 512, 512);
  conv(d_in[9],  Wh16[0][1], 1536, 512, 512);
  conv(d_in[17], Wh16[1][1], 1536, 512, 512);
  conv(d_in[20], wlin, 1024, 1024, 1024);
  conv(d_in[22], wgf, 1024, 2048, 2048);
  conv(d_in[24], wgf + (size_t)1024 * 2048, 1024, 2048, 2048);

  embed_kernel<<<Tt * Bb, 64, 0, stream>>>(context, tags, glove, bio, xt);

  GruParams GP;
  GP.xt = xt;
  // unit = layer*2 + dir
  GP.Wx[0] = Wx16[0][0]; GP.Wx[1] = Wx16[1][0]; GP.Wx[2] = Wx16[0][1]; GP.Wx[3] = Wx16[1][1];
  GP.Wh[0] = Wh16[0][0]; GP.Wh[1] = Wh16[1][0]; GP.Wh[2] = Wh16[0][1]; GP.Wh[3] = Wh16[1][1];
  GP.bih[0] = (const float*)d_in[6];  GP.bhh[0] = (const float*)d_in[7];
  GP.bih[1] = (const float*)d_in[14]; GP.bhh[1] = (const float*)d_in[15];
  GP.bih[2] = (const float*)d_in[10]; GP.bhh[2] = (const float*)d_in[11];
  GP.bih[3] = (const float*)d_in[18]; GP.bhh[3] = (const float*)d_in[19];
  GP.hb = hb;
  GP.allh = allh;
  GP.h1fin = h1fin;

  gru_persist<<<128, 256, 0, stream>>>(GP, flags);

  TArgs ga;
  // q = all_h @ W_lin^T + b_lin -> f16 qctx
  ga.A = allh; ga.A2 = allh; ga.B = wlin;
  ga.Ch = qctx; ga.Cf = nullptr; ga.bias = b_lin;
  ga.lda = 1024; ga.ldb = 1024; ga.ldc = 1024; ga.K = 1024; ga.Ksplit = 1 << 30;
  ga.sAz = 0; ga.sBz = 0; ga.sCz = 0;
  gemm_tiled<1><<<dim3(8, 256, 1), 256, 0, stream>>>(ga);

  // scores[b] = q[b] @ all_h[b]^T -> f32
  ga.A = qctx; ga.A2 = qctx; ga.B = allh;
  ga.Ch = nullptr; ga.Cf = scores; ga.bias = nullptr;
  ga.lda = 1024; ga.ldb = 1024; ga.ldc = 512; ga.K = 1024; ga.Ksplit = 1 << 30;
  ga.sAz = (long long)512 * 1024; ga.sBz = (long long)512 * 1024; ga.sCz = (long long)512 * 512;
  gemm_tiled<2><<<dim3(4, 4, 64), 256, 0, stream>>>(ga);

  softmax_rows<<<(Bb * Tt) / 4, 256, 0, stream>>>(scores, pmat);

  transpose_bt<<<dim3(32, 16, 64), dim3(32, 8), 0, stream>>>(allh, allhT);

  // ctx[b] = p[b] @ (all_hT[b])^T -> f16 (overwrites q in qctx)
  ga.A = pmat; ga.A2 = pmat; ga.B = allhT;
  ga.Ch = qctx; ga.Cf = nullptr; ga.bias = nullptr;
  ga.lda = 512; ga.ldb = 512; ga.ldc = 1024; ga.K = 512; ga.Ksplit = 1 << 30;
  ga.sAz = (long long)512 * 512; ga.sBz = (long long)1024 * 512; ga.sCz = (long long)512 * 1024;
  gemm_tiled<0><<<dim3(8, 4, 64), 256, 0, stream>>>(ga);

  // gf_pre = [ctx | all_h] @ Wgf^T -> f16 (overwrites allhT+scores region)
  ga.A = qctx; ga.A2 = allh; ga.B = wgf;
  ga.Ch = gfpre; ga.Cf = nullptr; ga.bias = nullptr;
  ga.lda = 1024; ga.ldb = 2048; ga.ldc = 2048; ga.K = 2048; ga.Ksplit = 1024;
  ga.sAz = 0; ga.sBz = 0; ga.sCz = 0;
  gemm_tiled<0><<<dim3(16, 256, 1), 256, 0, stream>>>(ga);

  float* out_attn = (float*)d_out + (size_t)Bb * D2H;
  gating<<<(Bb * Tt * 128) / 256, 256, 0, stream>>>(gfpre, allh, b_g, b_f, out_attn);

  write_concat<<<(Bb * D2H + 255) / 256, 256, 0, stream>>>(h1fin, (float*)d_out);
}

// Round 9
// 6872.185 us; speedup vs baseline: 1.8619x; 1.2195x over previous
//
#include <hip/hip_runtime.h>
#include <hip/hip_bf16.h>
#include <math.h>

typedef _Float16 f16x8 __attribute__((ext_vector_type(8)));
typedef float    f32x4 __attribute__((ext_vector_type(4)));

#define DEV __device__ __forceinline__

static constexpr int Ee   = 300;   // glove dim
static constexpr int INP  = 303;   // E + 3
static constexpr int INPP = 320;   // padded input dim
static constexpr int Hh   = 512;
static constexpr int Bb   = 64;
static constexpr int Tt   = 512;
static constexpr int D2H  = 1024;  // 2H
static constexpr int SLAB = Bb * Hh;  // one h-state slab (elements)

typedef const void __attribute__((address_space(1)))* gas_t;
typedef void __attribute__((address_space(3)))* las_t;

// ---- MFMA fragment load: K-major matrix M[row][k], frag[l][j] = M[row0+(l&15)][k0+8*(l>>4)+j]
DEV f16x8 ldfrag(const _Float16* base, int ld, int row0, int k0, int lane) {
  return *reinterpret_cast<const f16x8*>(base + (size_t)(row0 + (lane & 15)) * ld + (k0 + 8 * (lane >> 4)));
}
DEV float sigm(float x) { return 1.0f / (1.0f + expf(-x)); }

DEV void pollwait(const unsigned* p, unsigned tgt) {
  while (__hip_atomic_load(p, __ATOMIC_RELAXED, __HIP_MEMORY_SCOPE_AGENT) < tgt)
    __builtin_amdgcn_s_sleep(1);
}

// ---------------- weight convert (f32 -> f16, optional column pad) ----------------
__global__ void convert_pad(const float* __restrict__ src, _Float16* __restrict__ dst,
                            int rows, int csrc, int cdst) {
  int i = blockIdx.x * 256 + threadIdx.x;
  if (i >= rows * cdst) return;
  int r = i / cdst, c = i - r * cdst;
  dst[i] = (c < csrc) ? (_Float16)src[(size_t)r * csrc + c] : (_Float16)0.0f;
}

// ---------------- embedding: xt (T, B, INPP) f16 ----------------
__global__ void embed_kernel(const int* __restrict__ context, const int* __restrict__ tags,
                             const float* __restrict__ glove, const float* __restrict__ bio,
                             _Float16* __restrict__ xt) {
  int blk = blockIdx.x;            // t*64 + b
  int t = blk >> 6, b = blk & 63;
  int cid = context[b * Tt + t];   // context (B,T,1)
  int tag = tags[b * Tt + t];      // (B,T)
  _Float16* dst = xt + (size_t)blk * INPP;
  for (int c = threadIdx.x; c < INPP; c += 64) {
    float v = (c < Ee) ? glove[(size_t)cid * Ee + c]
                       : ((c < INP) ? bio[tag * 3 + (c - Ee)] : 0.0f);
    dst[c] = (_Float16)v;
  }
}

// ---------------- persistent GRU recurrence (r4 protocol, wave-specialized schedule) ----------------
// unit = layer*2 + dir. hb slabs: hb + ((size_t)t*4 + unit)*SLAB holds h_{t-1}
// (slab t=0 zeros). Step t reads slab t, write-through publishes slab t+1.
struct GruParams {
  const _Float16* xt;
  const _Float16* Wx[4];   // input-side weights (ld = 320 for L1, 512 for L2)
  const _Float16* Wh[4];   // hidden-side weights (ld = 512)
  const float* bih[4];
  const float* bhh[4];
  _Float16* hb;            // fresh h16 slabs, (Tt+1) x 4 x SLAB
  _Float16* allh;          // (B, T, 2H) f16
  float*    h1fin;         // [dir][64][512] fp32 layer-1 final states
};

// stage a 64KB slab into LDS with all 256 threads (prologue use)
DEV void stage64k(const char* __restrict__ gsrc, char* lbase, int tid) {
#pragma unroll
  for (int it = 0; it < 16; ++it) {
    int o = (it * 256 + tid) * 16;
    int row = o >> 10, boff = o & 1023;
    int srcOff = (row << 10) | (boff ^ ((row & 7) << 4));
    __builtin_amdgcn_global_load_lds((gas_t)(gsrc + srcOff), (las_t)(lbase + o), 16, 0, 0);
  }
}

// stage a 64KB slab with ONE wave (64 lanes x 64 iters), same swizzle
DEV void wstage(const _Float16* __restrict__ slab, _Float16* ldst, int lane) {
  const char* gsrc = (const char*)slab;
  char* lb = (char*)ldst;
#pragma unroll
  for (int it = 0; it < 64; ++it) {
    int o = (it * 64 + lane) * 16;
    int row = o >> 10, boff = o & 1023;
    int srcOff = (row << 10) | (boff ^ ((row & 7) << 4));
    __builtin_amdgcn_global_load_lds((gas_t)(gsrc + srcOff), (las_t)(lb + o), 16, 0, 0);
  }
}

// A-fragment read from a staged+swizzled 64x512 f16 LDS slab
DEV f16x8 ldsfrag(const char* lbase, int mt, int k0, int lane) {
  int row = mt * 16 + (lane & 15);
  int b = (k0 + 8 * (lane >> 4)) * 2;
  int addr = (row << 10) + (b ^ ((row & 7) << 4));
  return *reinterpret_cast<const f16x8*>(lbase + addr);
}

DEV void hside(f32x4* acc, const char* ldsbuf, const f16x8* wh, int lane) {
#pragma unroll
  for (int k = 0; k < 16; ++k) {
    f16x8 af[4];
#pragma unroll
    for (int mt = 0; mt < 4; ++mt) af[mt] = ldsfrag(ldsbuf, mt, k * 32, lane);
#pragma unroll
    for (int mt = 0; mt < 4; ++mt)
      acc[mt] = __builtin_amdgcn_mfma_f32_16x16x32_f16(af[mt], wh[k], acc[mt], 0, 0, 0);
  }
}

__global__ __launch_bounds__(256, 1) void gru_persist(GruParams P, unsigned* flags) {
  int unit = blockIdx.x >> 5;         // layer*2 + dir
  int blk  = blockIdx.x & 31;
  int cb   = blk << 4;                // h-column base
  int layer = unit >> 1, dir = unit & 1;
  unsigned* myFlag = flags + ((size_t)unit * 32 + blk) * 16;  // 64B/flag
  const unsigned* ownF = flags + (size_t)unit * 32 * 16;
  const unsigned* l1F  = flags + (size_t)dir  * 32 * 16;      // L1 unit of same dir

  int tid = threadIdx.x, w = tid >> 6, lane = tid & 63;
  // wave roles: 0 -> r (x+h), 1 -> z (x+h), 2 -> n_i (x only), 3 -> n_h (h only)
  int nrow = ((w == 0) ? 0 : (w == 1) ? Hh : 2 * Hh) + cb;

  const _Float16* Wx = P.Wx[unit];
  const _Float16* Wh = P.Wh[unit];
  const float* bih = P.bih[unit];
  const float* bhh = P.bhh[unit];

  int col = lane & 15;
  float bv;
  if      (w == 0) bv = bih[cb + col] + bhh[cb + col];
  else if (w == 1) bv = bih[Hh + cb + col] + bhh[Hh + cb + col];
  else if (w == 2) bv = bih[2 * Hh + cb + col];
  else             bv = bhh[2 * Hh + cb + col];

  __shared__ _Float16 ldsH[SLAB];     // 64KB: own hprev slab (staged by w3 each step)
  __shared__ _Float16 ldsX[SLAB];     // 64KB: L2 only — h1(t), prefetched by w2
  __shared__ float gl[4][64][20];     // gate pre-activations
  __shared__ float h32s[64][17];      // block-private fp32 h state
  for (int e = tid; e < 64 * 17; e += 256) ((float*)h32s)[e] = 0.0f;
  __syncthreads();

  int rbase = 4 * (lane >> 4);
  int erow = tid >> 2, ec0 = (tid & 3) << 2;  // epilogue: 4 cols/thread

  // ---- preload weights into registers ----
  f16x8 wxr[16], whr[16];
  if (w != 3) {
    if (layer == 0) {
#pragma unroll
      for (int k = 0; k < 10; ++k) wxr[k] = ldfrag(Wx, INPP, nrow, k * 32, lane);
    } else {
#pragma unroll
      for (int k = 0; k < 16; ++k) wxr[k] = ldfrag(Wx, Hh, nrow, k * 32, lane);
    }
  }
  if (w != 2) {
#pragma unroll
    for (int k = 0; k < 16; ++k) whr[k] = ldfrag(Wh, Hh, nrow, k * 32, lane);
  }

  // ---- prologue (L2 only): ldsX <- h1(0) = slab 1 of unit dir ----
  if (layer == 1) {
    if (tid < 32) pollwait(l1F + tid * 16, 1u);
    __syncthreads();
    stage64k((const char*)(P.hb + ((size_t)1 * 4 + dir) * SLAB), (char*)ldsX, tid);
    asm volatile("s_waitcnt vmcnt(0)" ::: "memory");
    __syncthreads();
  }

  for (int t = 0; t < Tt; ++t) {
    f32x4 acc[4] = {{0.f,0.f,0.f,0.f},{0.f,0.f,0.f,0.f},{0.f,0.f,0.f,0.f},{0.f,0.f,0.f,0.f}};

    // ---- Phase A: w3 polls own flags + stages ldsH; w0-w2 run x-side ----
    if (w == 3) {
      pollwait(ownF + (lane & 31) * 16, (unsigned)t);
      wstage(P.hb + ((size_t)t * 4 + unit) * SLAB, ldsH, lane);
      asm volatile("s_waitcnt vmcnt(0)" ::: "memory");   // per-wave: w3's stage done
    } else {
      if (layer == 0) {
        int tt = dir ? (Tt - 1 - t) : t;
        const _Float16* arow = P.xt + (size_t)tt * Bb * INPP + (lane & 15) * INPP + 8 * (lane >> 4);
#pragma unroll
        for (int k = 0; k < 10; ++k)
#pragma unroll
          for (int mt = 0; mt < 4; ++mt)
            acc[mt] = __builtin_amdgcn_mfma_f32_16x16x32_f16(
                *(const f16x8*)(arow + mt * 16 * INPP + k * 32), wxr[k], acc[mt], 0, 0, 0);
      } else {
        hside(acc, (const char*)ldsX, wxr, lane);   // x-side from staged h1(t)
      }
    }
    __syncthreads();   // ldsH ready; ldsX reads complete (free for prefetch)

    // ---- Phase B: w2 prefetches next h1 into ldsX (L2); w0,w1,w3 run h-side ----
    if (w == 2) {
      if (layer == 1 && t + 1 < Tt) {
        pollwait(l1F + (lane & 31) * 16, (unsigned)(t + 2));   // h1(t+1) = slab t+2
        wstage(P.hb + ((size_t)(t + 2) * 4 + dir) * SLAB, ldsX, lane);
        // no wait: drained by end-of-iteration vmcnt(0) + barrier
      }
    } else {
      hside(acc, (const char*)ldsH, whr, lane);
    }

#pragma unroll
    for (int mt = 0; mt < 4; ++mt)
#pragma unroll
      for (int r = 0; r < 4; ++r)
        gl[w][mt * 16 + rbase + r][col] = acc[mt][r] + bv;
    __syncthreads();

    // ---- epilogue: gates -> new h; publish write-through ----
    union { _Float16 h[4]; unsigned long long u; } pk;
    float hv[4];
#pragma unroll
    for (int j = 0; j < 4; ++j) {
      int c = ec0 + j;
      float rr = sigm(gl[0][erow][c]);
      float zz = sigm(gl[1][erow][c]);
      float nn = tanhf(gl[2][erow][c] + rr * gl[3][erow][c]);
      float hp = h32s[erow][c];
      hv[j] = (1.0f - zz) * nn + zz * hp;
      h32s[erow][c] = hv[j];
      pk.h[j] = (_Float16)hv[j];
    }
    _Float16* hout = P.hb + ((size_t)(t + 1) * 4 + unit) * SLAB + erow * Hh + cb + ec0;
    __hip_atomic_store((unsigned long long*)hout, pk.u, __ATOMIC_RELAXED, __HIP_MEMORY_SCOPE_AGENT);
    if (layer == 0 && t == Tt - 1)
      *(float4*)(P.h1fin + ((size_t)dir * Bb + erow) * Hh + cb + ec0) = make_float4(hv[0], hv[1], hv[2], hv[3]);

    asm volatile("s_waitcnt vmcnt(0)" ::: "memory");   // publish (and w2 prefetch) drained
    __syncthreads();
    if (tid == 0)
      __hip_atomic_store(myFlag, (unsigned)(t + 1), __ATOMIC_RELAXED, __HIP_MEMORY_SCOPE_AGENT);
    if (layer == 1)   // off the critical publish path; consumed post-kernel
      *(unsigned long long*)(P.allh + ((size_t)erow * Tt + t) * D2H + dir * Hh + cb + ec0) = pk.u;
  }
}

// ---------------- tiled TN GEMM: C = [A|A2](MxK, K-major) * B(NxK, K-major)^T ----------------
struct TArgs {
  const _Float16* A; const _Float16* A2; const _Float16* B;
  _Float16* Ch; float* Cf;
  const float* bias;
  int lda, ldb, ldc, K, Ksplit;
  long long sAz, sBz, sCz;
};

template<int MODE>  // 0: f16 out; 1: f16 out + bias; 2: f32 out
__global__ __launch_bounds__(256) void gemm_tiled(TArgs g) {
  int z = blockIdx.z;
  const _Float16* A  = g.A + (size_t)z * g.sAz;
  const _Float16* Bm = g.B + (size_t)z * g.sBz;
  int m0 = blockIdx.y * 128, n0 = blockIdx.x * 128;
  int tid = threadIdx.x, lane = tid & 63;
  int wr = (tid >> 7) & 1, wc = (tid >> 6) & 1;  // wave grid 2x2

  __shared__ _Float16 sA[2][128 * 64];
  __shared__ _Float16 sB[2][128 * 64];

  int ldab = g.lda * 2, ldbb = g.ldb * 2;

#define STAGE(buf, kt)                                                                   \
  {                                                                                      \
    int k0 = (kt) * 64;                                                                  \
    const _Float16* Asrc = A; int ka = k0;                                               \
    if (k0 >= g.Ksplit) { Asrc = g.A2; ka = k0 - g.Ksplit; }                             \
    const char* ab = (const char*)(Asrc + (size_t)m0 * g.lda + ka);                      \
    const char* bb = (const char*)(Bm  + (size_t)n0 * g.ldb + k0);                       \
    char* la = (char*)sA[buf]; char* lb = (char*)sB[buf];                                \
    _Pragma("unroll")                                                                    \
    for (int it = 0; it < 4; ++it) {                                                     \
      int o = (it * 256 + tid) * 16;                                                     \
      int row = o >> 7, boff = o & 127;                                                  \
      int sw = boff ^ ((row & 7) << 4);                                                  \
      __builtin_amdgcn_global_load_lds((gas_t)(ab + (size_t)row * ldab + sw),            \
                                       (las_t)(la + o), 16, 0, 0);                       \
      __builtin_amdgcn_global_load_lds((gas_t)(bb + (size_t)row * ldbb + sw),            \
                                       (las_t)(lb + o), 16, 0, 0);                       \
    }                                                                                    \
  }

  f32x4 acc[4][4] = {};
  int nkt = g.K / 64;
  STAGE(0, 0);
  asm volatile("s_waitcnt vmcnt(0)" ::: "memory");
  __syncthreads();

  int cbyte = (lane >> 4) << 4;  // 0,16,32,48
  for (int kt = 0; kt < nkt; ++kt) {
    int buf = kt & 1;
    if (kt + 1 < nkt) STAGE(buf ^ 1, kt + 1);
    const char* la = (const char*)sA[buf];
    const char* lb = (const char*)sB[buf];
    f16x8 af[2][4], bfr[2][4];
#pragma unroll
    for (int kk = 0; kk < 2; ++kk) {
#pragma unroll
      for (int mt = 0; mt < 4; ++mt) {
        int r = wr * 64 + mt * 16 + (lane & 15);
        int c = kk * 64 + cbyte;
        af[kk][mt] = *(const f16x8*)(la + r * 128 + (c ^ ((r & 7) << 4)));
      }
#pragma unroll
      for (int nt = 0; nt < 4; ++nt) {
        int r = wc * 64 + nt * 16 + (lane & 15);
        int c = kk * 64 + cbyte;
        bfr[kk][nt] = *(const f16x8*)(lb + r * 128 + (c ^ ((r & 7) << 4)));
      }
    }
#pragma unroll
    for (int kk = 0; kk < 2; ++kk)
#pragma unroll
      for (int mt = 0; mt < 4; ++mt)
#pragma unroll
        for (int nt = 0; nt < 4; ++nt)
          acc[mt][nt] = __builtin_amdgcn_mfma_f32_16x16x32_f16(af[kk][mt], bfr[kk][nt], acc[mt][nt], 0, 0, 0);
    asm volatile("s_waitcnt vmcnt(0)" ::: "memory");
    __syncthreads();
  }
#undef STAGE

  int rb = 4 * (lane >> 4);
#pragma unroll
  for (int nt = 0; nt < 4; ++nt) {
    int col = n0 + wc * 64 + nt * 16 + (lane & 15);
    float bv = (MODE == 1) ? g.bias[col] : 0.0f;
#pragma unroll
    for (int mt = 0; mt < 4; ++mt) {
#pragma unroll
      for (int r = 0; r < 4; ++r) {
        int row = m0 + wr * 64 + mt * 16 + rb + r;
        size_t idx = (size_t)z * g.sCz + (size_t)row * g.ldc + col;
        float v = acc[mt][nt][r] + bv;
        if (MODE == 2) g.Cf[idx] = v; else g.Ch[idx] = (_Float16)v;
      }
    }
  }
}

// ---------------- row softmax: scores f32 (.,512) -> p f16 ----------------
__global__ __launch_bounds__(256) void softmax_rows(const float* __restrict__ sc, _Float16* __restrict__ p) {
  int row = blockIdx.x * 4 + (threadIdx.x >> 6);
  int lane = threadIdx.x & 63;
  const float* s = sc + (size_t)row * 512 + lane * 8;
  float v[8];
  float4 q0 = *(const float4*)s, q1 = *(const float4*)(s + 4);
  v[0]=q0.x; v[1]=q0.y; v[2]=q0.z; v[3]=q0.w; v[4]=q1.x; v[5]=q1.y; v[6]=q1.z; v[7]=q1.w;
  float mx = v[0];
#pragma unroll
  for (int j = 1; j < 8; ++j) mx = fmaxf(mx, v[j]);
  for (int o = 32; o; o >>= 1) mx = fmaxf(mx, __shfl_xor(mx, o));
  float sum = 0.f;
#pragma unroll
  for (int j = 0; j < 8; ++j) { v[j] = expf(v[j] - mx); sum += v[j]; }
  for (int o = 32; o; o >>= 1) sum += __shfl_xor(sum, o);
  float inv = 1.0f / sum;
  _Float16* pd = p + (size_t)row * 512 + lane * 8;
#pragma unroll
  for (int j = 0; j < 8; ++j) pd[j] = (_Float16)(v[j] * inv);
}

// ---------------- per-batch transpose: allhT[b][d][t] = allh[b][t][d] ----------------
__global__ void transpose_bt(const _Float16* __restrict__ allh, _Float16* __restrict__ allhT) {
  __shared__ _Float16 tile[32][33];
  int b = blockIdx.z;
  int d0 = blockIdx.x * 32, t0 = blockIdx.y * 32;
  int tx = threadIdx.x, ty = threadIdx.y;  // (32, 8)
  const _Float16* in = allh + (size_t)b * Tt * D2H;
  _Float16* outp = allhT + (size_t)b * D2H * Tt;
#pragma unroll
  for (int j = 0; j < 4; ++j)
    tile[ty + 8 * j][tx] = in[(size_t)(t0 + ty + 8 * j) * D2H + d0 + tx];
  __syncthreads();
#pragma unroll
  for (int j = 0; j < 4; ++j)
    outp[(size_t)(d0 + ty + 8 * j) * Tt + t0 + tx] = tile[tx][ty + 8 * j];
}

// ---------------- gating epilogue: attn = g*f + (1-g)*allh ----------------
__global__ __launch_bounds__(256) void gating(const _Float16* __restrict__ gfpre,
                                              const _Float16* __restrict__ allh,
                                              const float* __restrict__ bg,
                                              const float* __restrict__ bfv,
                                              float* __restrict__ out_attn) {
  int i = blockIdx.x * 256 + threadIdx.x;   // over (B*T) * 128 groups
  int m = i >> 7, c0 = (i & 127) << 3;
  f16x8 gv = *(const f16x8*)(gfpre + (size_t)m * 2048 + c0);
  f16x8 fv = *(const f16x8*)(gfpre + (size_t)m * 2048 + 1024 + c0);
  f16x8 ah = *(const f16x8*)(allh + (size_t)m * D2H + c0);
  float res[8];
#pragma unroll
  for (int j = 0; j < 8; ++j) {
    float gg = sigm((float)gv[j] + bg[c0 + j]);
    float ff = tanhf((float)fv[j] + bfv[c0 + j]);
    res[j] = gg * ff + (1.0f - gg) * (float)ah[j];
  }
  float4* dst = (float4*)(out_attn + (size_t)m * D2H + c0);
  dst[0] = make_float4(res[0], res[1], res[2], res[3]);
  dst[1] = make_float4(res[4], res[5], res[6], res[7]);
}

// ---------------- final concat output ----------------
__global__ void write_concat(const float* __restrict__ h1fin, float* __restrict__ out) {
  int i = blockIdx.x * 256 + threadIdx.x;
  if (i >= Bb * D2H) return;
  int b = i >> 10, c = i & 1023;
  out[i] = (c < Hh) ? h1fin[(size_t)b * Hh + c] : h1fin[(size_t)(Bb + b) * Hh + (c - Hh)];
}

// =============================== host ===============================
extern "C" void kernel_launch(void* const* d_in, const int* in_sizes, int n_in,
                              void* d_out, int out_size, void* d_ws, size_t ws_size,
                              hipStream_t stream) {
  const int*   context = (const int*)d_in[0];
  const int*   tags    = (const int*)d_in[1];
  const float* glove   = (const float*)d_in[2];
  const float* bio     = (const float*)d_in[3];
  const float* b_lin   = (const float*)d_in[21];
  const float* b_g     = (const float*)d_in[23];
  const float* b_f     = (const float*)d_in[25];

  char* ws = (char*)d_ws;
  size_t off = 0;
  auto carve = [&](size_t bytes) -> void* {
    void* pp = ws + off;
    off = (off + bytes + 255) & ~(size_t)255;
    return pp;
  };

  _Float16* xt = (_Float16*)carve((size_t)Tt * Bb * INPP * 2);
  _Float16 *Wx16[2][2], *Wh16[2][2];
  Wx16[0][0] = (_Float16*)carve((size_t)1536 * 320 * 2);
  Wx16[1][0] = (_Float16*)carve((size_t)1536 * 320 * 2);
  Wx16[0][1] = (_Float16*)carve((size_t)1536 * 512 * 2);
  Wx16[1][1] = (_Float16*)carve((size_t)1536 * 512 * 2);
  for (int d = 0; d < 2; ++d)
    for (int l = 0; l < 2; ++l) Wh16[d][l] = (_Float16*)carve((size_t)1536 * 512 * 2);
  _Float16* wlin = (_Float16*)carve((size_t)1024 * 1024 * 2);
  _Float16* wgf  = (_Float16*)carve((size_t)2048 * 2048 * 2);
  _Float16* allh  = (_Float16*)carve((size_t)Bb * Tt * D2H * 2);      // 64 MiB
  _Float16* allhT = (_Float16*)carve((size_t)Bb * Tt * D2H * 2);      // 64 MiB (hb / gf_pre alias)
  float*    scores = (float*)carve((size_t)Bb * Tt * Tt * 4);          // 64 MiB (hb / gf_pre alias)
  _Float16* pmat   = (_Float16*)carve((size_t)Bb * Tt * Tt * 2);       // 32 MiB (hb tail alias)
  _Float16* qctx   = (_Float16*)carve((size_t)Bb * Tt * D2H * 2);      // q, then ctx
  float*    h1fin  = (float*)carve((size_t)2 * Bb * Hh * 4);
  unsigned* flags  = (unsigned*)carve((size_t)4 * 32 * 16 * 4);        // 8KB, 64B per block-flag

  // hb: (Tt+1)*4*SLAB*2 = 128.25 MiB, aliases allhT+scores+pmat-head (dead during recurrence)
  _Float16* hb = allhT;
  // gf_pre: 32768 x 2048 f16 = 128 MiB, aliases allhT+scores (dead by gf time)
  _Float16* gfpre = allhT;

  hipMemsetAsync(hb, 0, (size_t)4 * SLAB * 2, stream);          // slab t=0 (4 units) = 0
  hipMemsetAsync(flags, 0, (size_t)4 * 32 * 16 * 4, stream);    // progress flags

  auto conv = [&](const void* src, _Float16* dst, int rows, int csrc, int cdst) {
    int total = rows * cdst;
    convert_pad<<<(total + 255) / 256, 256, 0, stream>>>((const float*)src, dst, rows, csrc, cdst);
  };
  conv(d_in[4],  Wx16[0][0], 1536, 303, 320);
  conv(d_in[12], Wx16[1][0], 1536, 303, 320);
  conv(d_in[8],  Wx16[0][1], 1536, 512, 512);
  conv(d_in[16], Wx16[1][1], 1536, 512, 512);
  conv(d_in[5],  Wh16[0][0], 1536, 512, 512);
  conv(d_in[13], Wh16[1][0], 1536, 512, 512);
  conv(d_in[9],  Wh16[0][1], 1536, 512, 512);
  conv(d_in[17], Wh16[1][1], 1536, 512, 512);
  conv(d_in[20], wlin, 1024, 1024, 1024);
  conv(d_in[22], wgf, 1024, 2048, 2048);
  conv(d_in[24], wgf + (size_t)1024 * 2048, 1024, 2048, 2048);

  embed_kernel<<<Tt * Bb, 64, 0, stream>>>(context, tags, glove, bio, xt);

  GruParams GP;
  GP.xt = xt;
  // unit = layer*2 + dir
  GP.Wx[0] = Wx16[0][0]; GP.Wx[1] = Wx16[1][0]; GP.Wx[2] = Wx16[0][1]; GP.Wx[3] = Wx16[1][1];
  GP.Wh[0] = Wh16[0][0]; GP.Wh[1] = Wh16[1][0]; GP.Wh[2] = Wh16[0][1]; GP.Wh[3] = Wh16[1][1];
  GP.bih[0] = (const float*)d_in[6];  GP.bhh[0] = (const float*)d_in[7];
  GP.bih[1] = (const float*)d_in[14]; GP.bhh[1] = (const float*)d_in[15];
  GP.bih[2] = (const float*)d_in[10]; GP.bhh[2] = (const float*)d_in[11];
  GP.bih[3] = (const float*)d_in[18]; GP.bhh[3] = (const float*)d_in[19];
  GP.hb = hb;
  GP.allh = allh;
  GP.h1fin = h1fin;

  gru_persist<<<128, 256, 0, stream>>>(GP, flags);

  TArgs ga;
  // q = all_h @ W_lin^T + b_lin -> f16 qctx
  ga.A = allh; ga.A2 = allh; ga.B = wlin;
  ga.Ch = qctx; ga.Cf = nullptr; ga.bias = b_lin;
  ga.lda = 1024; ga.ldb = 1024; ga.ldc = 1024; ga.K = 1024; ga.Ksplit = 1 << 30;
  ga.sAz = 0; ga.sBz = 0; ga.sCz = 0;
  gemm_tiled<1><<<dim3(8, 256, 1), 256, 0, stream>>>(ga);

  // scores[b] = q[b] @ all_h[b]^T -> f32
  ga.A = qctx; ga.A2 = qctx; ga.B = allh;
  ga.Ch = nullptr; ga.Cf = scores; ga.bias = nullptr;
  ga.lda = 1024; ga.ldb = 1024; ga.ldc = 512; ga.K = 1024; ga.Ksplit = 1 << 30;
  ga.sAz = (long long)512 * 1024; ga.sBz = (long long)512 * 1024; ga.sCz = (long long)512 * 512;
  gemm_tiled<2><<<dim3(4, 4, 64), 256, 0, stream>>>(ga);

  softmax_rows<<<(Bb * Tt) / 4, 256, 0, stream>>>(scores, pmat);

  transpose_bt<<<dim3(32, 16, 64), dim3(32, 8), 0, stream>>>(allh, allhT);

  // ctx[b] = p[b] @ (all_hT[b])^T -> f16 (overwrites q in qctx)
  ga.A = pmat; ga.A2 = pmat; ga.B = allhT;
  ga.Ch = qctx; ga.Cf = nullptr; ga.bias = nullptr;
  ga.lda = 512; ga.ldb = 512; ga.ldc = 1024; ga.K = 512; ga.Ksplit = 1 << 30;
  ga.sAz = (long long)512 * 512; ga.sBz = (long long)1024 * 512; ga.sCz = (long long)512 * 1024;
  gemm_tiled<0><<<dim3(8, 4, 64), 256, 0, stream>>>(ga);

  // gf_pre = [ctx | all_h] @ Wgf^T -> f16 (overwrites allhT+scores region)
  ga.A = qctx; ga.A2 = allh; ga.B = wgf;
  ga.Ch = gfpre; ga.Cf = nullptr; ga.bias = nullptr;
  ga.lda = 1024; ga.ldb = 2048; ga.ldc = 2048; ga.K = 2048; ga.Ksplit = 1024;
  ga.sAz = 0; ga.sBz = 0; ga.sCz = 0;
  gemm_tiled<0><<<dim3(16, 256, 1), 256, 0, stream>>>(ga);

  float* out_attn = (float*)d_out + (size_t)Bb * D2H;
  gating<<<(Bb * Tt * 128) / 256, 256, 0, stream>>>(gfpre, allh, b_g, b_f, out_attn);

  write_concat<<<(Bb * D2H + 255) / 256, 256, 0, stream>>>(h1fin, (float*)d_out);
}

// Round 10
// 4756.374 us; speedup vs baseline: 2.6902x; 1.4448x over previous
//
#include <hip/hip_runtime.h>
#include <hip/hip_bf16.h>
#include <math.h>

typedef _Float16 f16x8 __attribute__((ext_vector_type(8)));
typedef float    f32x4 __attribute__((ext_vector_type(4)));

#define DEV __device__ __forceinline__

static constexpr int Ee   = 300;   // glove dim
static constexpr int INP  = 303;   // E + 3
static constexpr int INPP = 320;   // padded input dim
static constexpr int Hh   = 512;
static constexpr int Bb   = 64;
static constexpr int Tt   = 512;
static constexpr int D2H  = 1024;  // 2H
static constexpr int SLAB = Bb * Hh;  // one h-state slab (elements)

typedef const void __attribute__((address_space(1)))* gas_t;
typedef void __attribute__((address_space(3)))* las_t;

// ---- MFMA fragment load: K-major matrix M[row][k], frag[l][j] = M[row0+(l&15)][k0+8*(l>>4)+j]
DEV f16x8 ldfrag(const _Float16* base, int ld, int row0, int k0, int lane) {
  return *reinterpret_cast<const f16x8*>(base + (size_t)(row0 + (lane & 15)) * ld + (k0 + 8 * (lane >> 4)));
}
DEV float sigm(float x) { return 1.0f / (1.0f + expf(-x)); }

DEV void pollwait(const unsigned* p, unsigned tgt) {
  while (__hip_atomic_load(p, __ATOMIC_RELAXED, __HIP_MEMORY_SCOPE_AGENT) < tgt)
    __builtin_amdgcn_s_sleep(1);
}

// ---------------- weight convert (f32 -> f16, optional column pad) ----------------
__global__ void convert_pad(const float* __restrict__ src, _Float16* __restrict__ dst,
                            int rows, int csrc, int cdst) {
  int i = blockIdx.x * 256 + threadIdx.x;
  if (i >= rows * cdst) return;
  int r = i / cdst, c = i - r * cdst;
  dst[i] = (c < csrc) ? (_Float16)src[(size_t)r * csrc + c] : (_Float16)0.0f;
}

// ---------------- embedding: xt (T, B, INPP) f16 ----------------
__global__ void embed_kernel(const int* __restrict__ context, const int* __restrict__ tags,
                             const float* __restrict__ glove, const float* __restrict__ bio,
                             _Float16* __restrict__ xt) {
  int blk = blockIdx.x;            // t*64 + b
  int t = blk >> 6, b = blk & 63;
  int cid = context[b * Tt + t];   // context (B,T,1)
  int tag = tags[b * Tt + t];      // (B,T)
  _Float16* dst = xt + (size_t)blk * INPP;
  for (int c = threadIdx.x; c < INPP; c += 64) {
    float v = (c < Ee) ? glove[(size_t)cid * Ee + c]
                       : ((c < INP) ? bio[tag * 3 + (c - Ee)] : 0.0f);
    dst[c] = (_Float16)v;
  }
}

// ---------------- persistent GRU recurrence (r5 protocol; L2 ldsX prefetched) ----------------
// unit = layer*2 + dir. hb slabs: hb + ((size_t)t*4 + unit)*SLAB holds h_{t-1}
// (slab t=0 zeros). Step t reads slab t, write-through publishes slab t+1.
struct GruParams {
  const _Float16* xt;
  const _Float16* Wx[4];   // input-side weights (ld = 320 for L1, 512 for L2)
  const _Float16* Wh[4];   // hidden-side weights (ld = 512)
  const float* bih[4];
  const float* bhh[4];
  _Float16* hb;            // fresh h16 slabs, (Tt+1) x 4 x SLAB
  _Float16* allh;          // (B, T, 2H) f16
  float*    h1fin;         // [dir][64][512] fp32 layer-1 final states
};

// stage a 64KB slab (64x512 f16) into LDS, linear dest, inverse-swizzled source.
// cooperative: all 256 threads (4 waves issue DMA in parallel) — the proven r4/r5 form.
DEV void stage64k(const char* __restrict__ gsrc, char* lbase, int tid) {
#pragma unroll
  for (int it = 0; it < 16; ++it) {
    int o = (it * 256 + tid) * 16;
    int row = o >> 10, boff = o & 1023;
    int srcOff = (row << 10) | (boff ^ ((row & 7) << 4));
    __builtin_amdgcn_global_load_lds((gas_t)(gsrc + srcOff), (las_t)(lbase + o), 16, 0, 0);
  }
}

// A-fragment read from a staged+swizzled 64x512 f16 LDS slab
DEV f16x8 ldsfrag(const char* lbase, int mt, int k0, int lane) {
  int row = mt * 16 + (lane & 15);
  int b = (k0 + 8 * (lane >> 4)) * 2;
  int addr = (row << 10) + (b ^ ((row & 7) << 4));
  return *reinterpret_cast<const f16x8*>(lbase + addr);
}

DEV void hside(f32x4* acc, const char* ldsbuf, const f16x8* wh, int lane) {
#pragma unroll
  for (int k = 0; k < 16; ++k) {
    f16x8 af[4];
#pragma unroll
    for (int mt = 0; mt < 4; ++mt) af[mt] = ldsfrag(ldsbuf, mt, k * 32, lane);
#pragma unroll
    for (int mt = 0; mt < 4; ++mt)
      acc[mt] = __builtin_amdgcn_mfma_f32_16x16x32_f16(af[mt], wh[k], acc[mt], 0, 0, 0);
  }
}

__global__ __launch_bounds__(256, 1) void gru_persist(GruParams P, unsigned* flags) {
  int unit = blockIdx.x >> 5;         // layer*2 + dir
  int blk  = blockIdx.x & 31;
  int cb   = blk << 4;                // h-column base
  int layer = unit >> 1, dir = unit & 1;
  unsigned* myFlag = flags + ((size_t)unit * 32 + blk) * 16;  // 64B/flag
  const unsigned* ownF = flags + (size_t)unit * 32 * 16;
  const unsigned* l1F  = flags + (size_t)dir  * 32 * 16;      // L1 unit of same dir

  int tid = threadIdx.x, w = tid >> 6, lane = tid & 63;
  // wave roles: 0 -> r, 1 -> z, 2 -> n_i (x-side only), 3 -> n_h (h-side only)
  int nrow = ((w == 0) ? 0 : (w == 1) ? Hh : 2 * Hh) + cb;

  const _Float16* Wx = P.Wx[unit];
  const _Float16* Wh = P.Wh[unit];
  const float* bih = P.bih[unit];
  const float* bhh = P.bhh[unit];

  int col = lane & 15;
  float bv;
  if      (w == 0) bv = bih[cb + col] + bhh[cb + col];
  else if (w == 1) bv = bih[Hh + cb + col] + bhh[Hh + cb + col];
  else if (w == 2) bv = bih[2 * Hh + cb + col];
  else             bv = bhh[2 * Hh + cb + col];

  __shared__ _Float16 ldsH[SLAB];     // 64KB staged hprev
  __shared__ _Float16 ldsX[SLAB];     // 64KB staged h1 (L2 only; prefetched 1 step ahead)
  __shared__ float gl[4][64][20];     // gate pre-activations
  __shared__ float h32s[64][17];      // block-private fp32 h state
  for (int e = tid; e < 64 * 17; e += 256) ((float*)h32s)[e] = 0.0f;
  __syncthreads();

  int rbase = 4 * (lane >> 4);
  int erow = tid >> 2, ec0 = (tid & 3) << 2;

#define GLWRITE(ACC)                                          \
  _Pragma("unroll")                                           \
  for (int mt = 0; mt < 4; ++mt)                              \
    _Pragma("unroll")                                         \
    for (int r = 0; r < 4; ++r)                               \
      gl[w][mt * 16 + rbase + r][col] = (ACC)[mt][r] + bv;

  union PkU { _Float16 h[4]; unsigned long long u; };

  if (layer == 0) {
    f16x8 wxr[10], whr[16];
    if (w != 3) {
#pragma unroll
      for (int k = 0; k < 10; ++k) wxr[k] = ldfrag(Wx, INPP, nrow, k * 32, lane);
    }
    if (w != 2) {
#pragma unroll
      for (int k = 0; k < 16; ++k) whr[k] = ldfrag(Wh, Hh, nrow, k * 32, lane);
    }
    for (int t = 0; t < Tt; ++t) {
      f32x4 acc[4] = {{0.f,0.f,0.f,0.f},{0.f,0.f,0.f,0.f},{0.f,0.f,0.f,0.f},{0.f,0.f,0.f,0.f}};
      // x-side first: overlaps flag propagation from siblings
      if (w != 3) {
        int tt = dir ? (Tt - 1 - t) : t;
        const _Float16* arow = P.xt + (size_t)tt * Bb * INPP + (lane & 15) * INPP + 8 * (lane >> 4);
#pragma unroll
        for (int k = 0; k < 10; ++k)
#pragma unroll
          for (int mt = 0; mt < 4; ++mt)
            acc[mt] = __builtin_amdgcn_mfma_f32_16x16x32_f16(
                *(const f16x8*)(arow + mt * 16 * INPP + k * 32), wxr[k], acc[mt], 0, 0, 0);
      }
      if (tid < 32) pollwait(ownF + tid * 16, (unsigned)t);
      __syncthreads();
      stage64k((const char*)(P.hb + ((size_t)t * 4 + unit) * SLAB), (char*)ldsH, tid);
      asm volatile("s_waitcnt vmcnt(0)" ::: "memory");
      __syncthreads();
      if (w != 2) hside(acc, (const char*)ldsH, whr, lane);
      GLWRITE(acc);
      __syncthreads();

      PkU pk; float hv[4];
#pragma unroll
      for (int j = 0; j < 4; ++j) {
        int c = ec0 + j;
        float rr = sigm(gl[0][erow][c]);
        float zz = sigm(gl[1][erow][c]);
        float nn = tanhf(gl[2][erow][c] + rr * gl[3][erow][c]);
        float hp = h32s[erow][c];
        hv[j] = (1.0f - zz) * nn + zz * hp;
        h32s[erow][c] = hv[j];
        pk.h[j] = (_Float16)hv[j];
      }
      _Float16* hout = P.hb + ((size_t)(t + 1) * 4 + unit) * SLAB + erow * Hh + cb + ec0;
      __hip_atomic_store((unsigned long long*)hout, pk.u, __ATOMIC_RELAXED, __HIP_MEMORY_SCOPE_AGENT);
      if (t == Tt - 1)
        *(float4*)(P.h1fin + ((size_t)dir * Bb + erow) * Hh + cb + ec0) = make_float4(hv[0], hv[1], hv[2], hv[3]);

      asm volatile("s_waitcnt vmcnt(0)" ::: "memory");   // publish drained to coherence point
      __syncthreads();
      if (tid == 0)
        __hip_atomic_store(myFlag, (unsigned)(t + 1), __ATOMIC_RELAXED, __HIP_MEMORY_SCOPE_AGENT);
    }
  } else {
    f16x8 wxr[16], whr[16];
    if (w != 3) {
#pragma unroll
      for (int k = 0; k < 16; ++k) wxr[k] = ldfrag(Wx, Hh, nrow, k * 32, lane);
    }
    if (w != 2) {
#pragma unroll
      for (int k = 0; k < 16; ++k) whr[k] = ldfrag(Wh, Hh, nrow, k * 32, lane);
    }

    // ---- prologue: ldsX <- h1(0) (slab 1 of L1 unit), 4-wave cooperative ----
    if (tid < 32) pollwait(l1F + tid * 16, 1u);
    __syncthreads();
    stage64k((const char*)(P.hb + ((size_t)1 * 4 + dir) * SLAB), (char*)ldsX, tid);
    asm volatile("s_waitcnt vmcnt(0)" ::: "memory");
    __syncthreads();

    for (int t = 0; t < Tt; ++t) {
      // wait: own siblings >= t (h1(t) already in ldsX from prefetch/prologue)
      if (tid < 32) pollwait(ownF + tid * 16, (unsigned)t);
      __syncthreads();
      stage64k((const char*)(P.hb + ((size_t)t * 4 + unit) * SLAB), (char*)ldsH, tid);  // own hprev
      asm volatile("s_waitcnt vmcnt(0)" ::: "memory");
      __syncthreads();

      f32x4 acc[4] = {{0.f,0.f,0.f,0.f},{0.f,0.f,0.f,0.f},{0.f,0.f,0.f,0.f},{0.f,0.f,0.f,0.f}};
      if (w != 3) hside(acc, (const char*)ldsX, wxr, lane);   // x-side: h1(t)
      if (w != 2) hside(acc, (const char*)ldsH, whr, lane);   // h-side: own hprev
      GLWRITE(acc);
      __syncthreads();   // ldsX reads complete; gl written

      // ---- prefetch ldsX <- h1(t+1) (slab t+2), off-chain: L1 leads, poll instant ----
      if (t + 1 < Tt) {
        if (tid < 32) pollwait(l1F + tid * 16, (unsigned)(t + 2));
        __syncthreads();
        stage64k((const char*)(P.hb + ((size_t)(t + 2) * 4 + dir) * SLAB), (char*)ldsX, tid);
        // no wait here: drained by the epilogue vmcnt(0) below
      }

      PkU pk; float hv[4];
#pragma unroll
      for (int j = 0; j < 4; ++j) {
        int c = ec0 + j;
        float rr = sigm(gl[0][erow][c]);
        float zz = sigm(gl[1][erow][c]);
        float nn = tanhf(gl[2][erow][c] + rr * gl[3][erow][c]);
        float hp = h32s[erow][c];
        hv[j] = (1.0f - zz) * nn + zz * hp;
        h32s[erow][c] = hv[j];
        pk.h[j] = (_Float16)hv[j];
      }
      _Float16* hout = P.hb + ((size_t)(t + 1) * 4 + unit) * SLAB + erow * Hh + cb + ec0;
      __hip_atomic_store((unsigned long long*)hout, pk.u, __ATOMIC_RELAXED, __HIP_MEMORY_SCOPE_AGENT);

      asm volatile("s_waitcnt vmcnt(0)" ::: "memory");   // drains publish + prefetch DMA
      __syncthreads();
      if (tid == 0)
        __hip_atomic_store(myFlag, (unsigned)(t + 1), __ATOMIC_RELAXED, __HIP_MEMORY_SCOPE_AGENT);
      // allh publication off the critical publish path (consumed post-kernel)
      *(unsigned long long*)(P.allh + ((size_t)erow * Tt + t) * D2H + dir * Hh + cb + ec0) = pk.u;
    }
  }
#undef GLWRITE
}

// ---------------- tiled TN GEMM: C = [A|A2](MxK, K-major) * B(NxK, K-major)^T ----------------
struct TArgs {
  const _Float16* A; const _Float16* A2; const _Float16* B;
  _Float16* Ch; float* Cf;
  const float* bias;
  int lda, ldb, ldc, K, Ksplit;
  long long sAz, sBz, sCz;
};

template<int MODE>  // 0: f16 out; 1: f16 out + bias; 2: f32 out
__global__ __launch_bounds__(256) void gemm_tiled(TArgs g) {
  int z = blockIdx.z;
  const _Float16* A  = g.A + (size_t)z * g.sAz;
  const _Float16* Bm = g.B + (size_t)z * g.sBz;
  int m0 = blockIdx.y * 128, n0 = blockIdx.x * 128;
  int tid = threadIdx.x, lane = tid & 63;
  int wr = (tid >> 7) & 1, wc = (tid >> 6) & 1;  // wave grid 2x2

  __shared__ _Float16 sA[2][128 * 64];
  __shared__ _Float16 sB[2][128 * 64];

  int ldab = g.lda * 2, ldbb = g.ldb * 2;

#define STAGE(buf, kt)                                                                   \
  {                                                                                      \
    int k0 = (kt) * 64;                                                                  \
    const _Float16* Asrc = A; int ka = k0;                                               \
    if (k0 >= g.Ksplit) { Asrc = g.A2; ka = k0 - g.Ksplit; }                             \
    const char* ab = (const char*)(Asrc + (size_t)m0 * g.lda + ka);                      \
    const char* bb = (const char*)(Bm  + (size_t)n0 * g.ldb + k0);                       \
    char* la = (char*)sA[buf]; char* lb = (char*)sB[buf];                                \
    _Pragma("unroll")                                                                    \
    for (int it = 0; it < 4; ++it) {                                                     \
      int o = (it * 256 + tid) * 16;                                                     \
      int row = o >> 7, boff = o & 127;                                                  \
      int sw = boff ^ ((row & 7) << 4);                                                  \
      __builtin_amdgcn_global_load_lds((gas_t)(ab + (size_t)row * ldab + sw),            \
                                       (las_t)(la + o), 16, 0, 0);                       \
      __builtin_amdgcn_global_load_lds((gas_t)(bb + (size_t)row * ldbb + sw),            \
                                       (las_t)(lb + o), 16, 0, 0);                       \
    }                                                                                    \
  }

  f32x4 acc[4][4] = {};
  int nkt = g.K / 64;
  STAGE(0, 0);
  asm volatile("s_waitcnt vmcnt(0)" ::: "memory");
  __syncthreads();

  int cbyte = (lane >> 4) << 4;  // 0,16,32,48
  for (int kt = 0; kt < nkt; ++kt) {
    int buf = kt & 1;
    if (kt + 1 < nkt) STAGE(buf ^ 1, kt + 1);
    const char* la = (const char*)sA[buf];
    const char* lb = (const char*)sB[buf];
    f16x8 af[2][4], bfr[2][4];
#pragma unroll
    for (int kk = 0; kk < 2; ++kk) {
#pragma unroll
      for (int mt = 0; mt < 4; ++mt) {
        int r = wr * 64 + mt * 16 + (lane & 15);
        int c = kk * 64 + cbyte;
        af[kk][mt] = *(const f16x8*)(la + r * 128 + (c ^ ((r & 7) << 4)));
      }
#pragma unroll
      for (int nt = 0; nt < 4; ++nt) {
        int r = wc * 64 + nt * 16 + (lane & 15);
        int c = kk * 64 + cbyte;
        bfr[kk][nt] = *(const f16x8*)(lb + r * 128 + (c ^ ((r & 7) << 4)));
      }
    }
#pragma unroll
    for (int kk = 0; kk < 2; ++kk)
#pragma unroll
      for (int mt = 0; mt < 4; ++mt)
#pragma unroll
        for (int nt = 0; nt < 4; ++nt)
          acc[mt][nt] = __builtin_amdgcn_mfma_f32_16x16x32_f16(af[kk][mt], bfr[kk][nt], acc[mt][nt], 0, 0, 0);
    asm volatile("s_waitcnt vmcnt(0)" ::: "memory");
    __syncthreads();
  }
#undef STAGE

  int rb = 4 * (lane >> 4);
#pragma unroll
  for (int nt = 0; nt < 4; ++nt) {
    int col = n0 + wc * 64 + nt * 16 + (lane & 15);
    float bv = (MODE == 1) ? g.bias[col] : 0.0f;
#pragma unroll
    for (int mt = 0; mt < 4; ++mt) {
#pragma unroll
      for (int r = 0; r < 4; ++r) {
        int row = m0 + wr * 64 + mt * 16 + rb + r;
        size_t idx = (size_t)z * g.sCz + (size_t)row * g.ldc + col;
        float v = acc[mt][nt][r] + bv;
        if (MODE == 2) g.Cf[idx] = v; else g.Ch[idx] = (_Float16)v;
      }
    }
  }
}

// ---------------- row softmax: scores f32 (.,512) -> p f16 ----------------
__global__ __launch_bounds__(256) void softmax_rows(const float* __restrict__ sc, _Float16* __restrict__ p) {
  int row = blockIdx.x * 4 + (threadIdx.x >> 6);
  int lane = threadIdx.x & 63;
  const float* s = sc + (size_t)row * 512 + lane * 8;
  float v[8];
  float4 q0 = *(const float4*)s, q1 = *(const float4*)(s + 4);
  v[0]=q0.x; v[1]=q0.y; v[2]=q0.z; v[3]=q0.w; v[4]=q1.x; v[5]=q1.y; v[6]=q1.z; v[7]=q1.w;
  float mx = v[0];
#pragma unroll
  for (int j = 1; j < 8; ++j) mx = fmaxf(mx, v[j]);
  for (int o = 32; o; o >>= 1) mx = fmaxf(mx, __shfl_xor(mx, o));
  float sum = 0.f;
#pragma unroll
  for (int j = 0; j < 8; ++j) { v[j] = expf(v[j] - mx); sum += v[j]; }
  for (int o = 32; o; o >>= 1) sum += __shfl_xor(sum, o);
  float inv = 1.0f / sum;
  _Float16* pd = p + (size_t)row * 512 + lane * 8;
#pragma unroll
  for (int j = 0; j < 8; ++j) pd[j] = (_Float16)(v[j] * inv);
}

// ---------------- per-batch transpose: allhT[b][d][t] = allh[b][t][d] ----------------
__global__ void transpose_bt(const _Float16* __restrict__ allh, _Float16* __restrict__ allhT) {
  __shared__ _Float16 tile[32][33];
  int b = blockIdx.z;
  int d0 = blockIdx.x * 32, t0 = blockIdx.y * 32;
  int tx = threadIdx.x, ty = threadIdx.y;  // (32, 8)
  const _Float16* in = allh + (size_t)b * Tt * D2H;
  _Float16* outp = allhT + (size_t)b * D2H * Tt;
#pragma unroll
  for (int j = 0; j < 4; ++j)
    tile[ty + 8 * j][tx] = in[(size_t)(t0 + ty + 8 * j) * D2H + d0 + tx];
  __syncthreads();
#pragma unroll
  for (int j = 0; j < 4; ++j)
    outp[(size_t)(d0 + ty + 8 * j) * Tt + t0 + tx] = tile[tx][ty + 8 * j];
}

// ---------------- gating epilogue: attn = g*f + (1-g)*allh ----------------
__global__ __launch_bounds__(256) void gating(const _Float16* __restrict__ gfpre,
                                              const _Float16* __restrict__ allh,
                                              const float* __restrict__ bg,
                                              const float* __restrict__ bfv,
                                              float* __restrict__ out_attn) {
  int i = blockIdx.x * 256 + threadIdx.x;   // over (B*T) * 128 groups
  int m = i >> 7, c0 = (i & 127) << 3;
  f16x8 gv = *(const f16x8*)(gfpre + (size_t)m * 2048 + c0);
  f16x8 fv = *(const f16x8*)(gfpre + (size_t)m * 2048 + 1024 + c0);
  f16x8 ah = *(const f16x8*)(allh + (size_t)m * D2H + c0);
  float res[8];
#pragma unroll
  for (int j = 0; j < 8; ++j) {
    float gg = sigm((float)gv[j] + bg[c0 + j]);
    float ff = tanhf((float)fv[j] + bfv[c0 + j]);
    res[j] = gg * ff + (1.0f - gg) * (float)ah[j];
  }
  float4* dst = (float4*)(out_attn + (size_t)m * D2H + c0);
  dst[0] = make_float4(res[0], res[1], res[2], res[3]);
  dst[1] = make_float4(res[4], res[5], res[6], res[7]);
}

// ---------------- final concat output ----------------
__global__ void write_concat(const float* __restrict__ h1fin, float* __restrict__ out) {
  int i = blockIdx.x * 256 + threadIdx.x;
  if (i >= Bb * D2H) return;
  int b = i >> 10, c = i & 1023;
  out[i] = (c < Hh) ? h1fin[(size_t)b * Hh + c] : h1fin[(size_t)(Bb + b) * Hh + (c - Hh)];
}

// =============================== host ===============================
extern "C" void kernel_launch(void* const* d_in, const int* in_sizes, int n_in,
                              void* d_out, int out_size, void* d_ws, size_t ws_size,
                              hipStream_t stream) {
  const int*   context = (const int*)d_in[0];
  const int*   tags    = (const int*)d_in[1];
  const float* glove   = (const float*)d_in[2];
  const float* bio     = (const float*)d_in[3];
  const float* b_lin   = (const float*)d_in[21];
  const float* b_g     = (const float*)d_in[23];
  const float* b_f     = (const float*)d_in[25];

  char* ws = (char*)d_ws;
  size_t off = 0;
  auto carve = [&](size_t bytes) -> void* {
    void* pp = ws + off;
    off = (off + bytes + 255) & ~(size_t)255;
    return pp;
  };

  _Float16* xt = (_Float16*)carve((size_t)Tt * Bb * INPP * 2);
  _Float16 *Wx16[2][2], *Wh16[2][2];
  Wx16[0][0] = (_Float16*)carve((size_t)1536 * 320 * 2);
  Wx16[1][0] = (_Float16*)carve((size_t)1536 * 320 * 2);
  Wx16[0][1] = (_Float16*)carve((size_t)1536 * 512 * 2);
  Wx16[1][1] = (_Float16*)carve((size_t)1536 * 512 * 2);
  for (int d = 0; d < 2; ++d)
    for (int l = 0; l < 2; ++l) Wh16[d][l] = (_Float16*)carve((size_t)1536 * 512 * 2);
  _Float16* wlin = (_Float16*)carve((size_t)1024 * 1024 * 2);
  _Float16* wgf  = (_Float16*)carve((size_t)2048 * 2048 * 2);
  _Float16* allh  = (_Float16*)carve((size_t)Bb * Tt * D2H * 2);      // 64 MiB
  _Float16* allhT = (_Float16*)carve((size_t)Bb * Tt * D2H * 2);      // 64 MiB (hb / gf_pre alias)
  float*    scores = (float*)carve((size_t)Bb * Tt * Tt * 4);          // 64 MiB (hb / gf_pre alias)
  _Float16* pmat   = (_Float16*)carve((size_t)Bb * Tt * Tt * 2);       // 32 MiB (hb tail alias)
  _Float16* qctx   = (_Float16*)carve((size_t)Bb * Tt * D2H * 2);      // q, then ctx
  float*    h1fin  = (float*)carve((size_t)2 * Bb * Hh * 4);
  unsigned* flags  = (unsigned*)carve((size_t)4 * 32 * 16 * 4);        // 8KB, 64B per block-flag

  // hb: (Tt+1)*4*SLAB*2 = 128.25 MiB, aliases allhT+scores+pmat-head (dead during recurrence)
  _Float16* hb = allhT;
  // gf_pre: 32768 x 2048 f16 = 128 MiB, aliases allhT+scores (dead by gf time)
  _Float16* gfpre = allhT;

  hipMemsetAsync(hb, 0, (size_t)4 * SLAB * 2, stream);          // slab t=0 (4 units) = 0
  hipMemsetAsync(flags, 0, (size_t)4 * 32 * 16 * 4, stream);    // progress flags

  auto conv = [&](const void* src, _Float16* dst, int rows, int csrc, int cdst) {
    int total = rows * cdst;
    convert_pad<<<(total + 255) / 256, 256, 0, stream>>>((const float*)src, dst, rows, csrc, cdst);
  };
  conv(d_in[4],  Wx16[0][0], 1536, 303, 320);
  conv(d_in[12], Wx16[1][0], 1536, 303, 320);
  conv(d_in[8],  Wx16[0][1], 1536, 512, 512);
  conv(d_in[16], Wx16[1][1], 1536, 512, 512);
  conv(d_in[5],  Wh16[0][0], 1536, 512, 512);
  conv(d_in[13], Wh16[1][0], 1536, 512, 512);
  conv(d_in[9],  Wh16[0][1], 1536, 512, 512);
  conv(d_in[17], Wh16[1][1], 1536, 512, 512);
  conv(d_in[20], wlin, 1024, 1024, 1024);
  conv(d_in[22], wgf, 1024, 2048, 2048);
  conv(d_in[24], wgf + (size_t)1024 * 2048, 1024, 2048, 2048);

  embed_kernel<<<Tt * Bb, 64, 0, stream>>>(context, tags, glove, bio, xt);

  GruParams GP;
  GP.xt = xt;
  // unit = layer*2 + dir
  GP.Wx[0] = Wx16[0][0]; GP.Wx[1] = Wx16[1][0]; GP.Wx[2] = Wx16[0][1]; GP.Wx[3] = Wx16[1][1];
  GP.Wh[0] = Wh16[0][0]; GP.Wh[1] = Wh16[1][0]; GP.Wh[2] = Wh16[0][1]; GP.Wh[3] = Wh16[1][1];
  GP.bih[0] = (const float*)d_in[6];  GP.bhh[0] = (const float*)d_in[7];
  GP.bih[1] = (const float*)d_in[14]; GP.bhh[1] = (const float*)d_in[15];
  GP.bih[2] = (const float*)d_in[10]; GP.bhh[2] = (const float*)d_in[11];
  GP.bih[3] = (const float*)d_in[18]; GP.bhh[3] = (const float*)d_in[19];
  GP.hb = hb;
  GP.allh = allh;
  GP.h1fin = h1fin;

  gru_persist<<<128, 256, 0, stream>>>(GP, flags);

  TArgs ga;
  // q = all_h @ W_lin^T + b_lin -> f16 qctx
  ga.A = allh; ga.A2 = allh; ga.B = wlin;
  ga.Ch = qctx; ga.Cf = nullptr; ga.bias = b_lin;
  ga.lda = 1024; ga.ldb = 1024; ga.ldc = 1024; ga.K = 1024; ga.Ksplit = 1 << 30;
  ga.sAz = 0; ga.sBz = 0; ga.sCz = 0;
  gemm_tiled<1><<<dim3(8, 256, 1), 256, 0, stream>>>(ga);

  // scores[b] = q[b] @ all_h[b]^T -> f32
  ga.A = qctx; ga.A2 = qctx; ga.B = allh;
  ga.Ch = nullptr; ga.Cf = scores; ga.bias = nullptr;
  ga.lda = 1024; ga.ldb = 1024; ga.ldc = 512; ga.K = 1024; ga.Ksplit = 1 << 30;
  ga.sAz = (long long)512 * 1024; ga.sBz = (long long)512 * 1024; ga.sCz = (long long)512 * 512;
  gemm_tiled<2><<<dim3(4, 4, 64), 256, 0, stream>>>(ga);

  softmax_rows<<<(Bb * Tt) / 4, 256, 0, stream>>>(scores, pmat);

  transpose_bt<<<dim3(32, 16, 64), dim3(32, 8), 0, stream>>>(allh, allhT);

  // ctx[b] = p[b] @ (all_hT[b])^T -> f16 (overwrites q in qctx)
  ga.A = pmat; ga.A2 = pmat; ga.B = allhT;
  ga.Ch = qctx; ga.Cf = nullptr; ga.bias = nullptr;
  ga.lda = 512; ga.ldb = 512; ga.ldc = 1024; ga.K = 512; ga.Ksplit = 1 << 30;
  ga.sAz = (long long)512 * 512; ga.sBz = (long long)1024 * 512; ga.sCz = (long long)512 * 1024;
  gemm_tiled<0><<<dim3(8, 4, 64), 256, 0, stream>>>(ga);

  // gf_pre = [ctx | all_h] @ Wgf^T -> f16 (overwrites allhT+scores region)
  ga.A = qctx; ga.A2 = allh; ga.B = wgf;
  ga.Ch = gfpre; ga.Cf = nullptr; ga.bias = nullptr;
  ga.lda = 1024; ga.ldb = 2048; ga.ldc = 2048; ga.K = 2048; ga.Ksplit = 1024;
  ga.sAz = 0; ga.sBz = 0; ga.sCz = 0;
  gemm_tiled<0><<<dim3(16, 256, 1), 256, 0, stream>>>(ga);

  float* out_attn = (float*)d_out + (size_t)Bb * D2H;
  gating<<<(Bb * Tt * 128) / 256, 256, 0, stream>>>(gfpre, allh, b_g, b_f, out_attn);

  write_concat<<<(Bb * D2H + 255) / 256, 256, 0, stream>>>(h1fin, (float*)d_out);
}

// Round 11
// 2955.531 us; speedup vs baseline: 4.3294x; 1.6093x over previous
//
#include <hip/hip_runtime.h>
#include <hip/hip_bf16.h>
#include <math.h>

typedef _Float16 f16x8 __attribute__((ext_vector_type(8)));
typedef float    f32x4 __attribute__((ext_vector_type(4)));

#define DEV __device__ __forceinline__

static constexpr int Ee   = 300;   // glove dim
static constexpr int INP  = 303;   // E + 3
static constexpr int INPP = 320;   // padded input dim
static constexpr int Hh   = 512;
static constexpr int Bb   = 64;
static constexpr int Tt   = 512;
static constexpr int D2H  = 1024;  // 2H
static constexpr int RB   = 16;    // batch rows per chain
static constexpr int SLAB16 = RB * Hh;  // 8192 elems = 16KB

typedef const void __attribute__((address_space(1)))* gas_t;
typedef void __attribute__((address_space(3)))* las_t;

// ---- MFMA fragment load: K-major matrix M[row][k], frag[l][j] = M[row0+(l&15)][k0+8*(l>>4)+j]
DEV f16x8 ldfrag(const _Float16* base, int ld, int row0, int k0, int lane) {
  return *reinterpret_cast<const f16x8*>(base + (size_t)(row0 + (lane & 15)) * ld + (k0 + 8 * (lane >> 4)));
}
DEV float sigm(float x) { return 1.0f / (1.0f + expf(-x)); }

DEV void pollwait(const unsigned* p, unsigned tgt) {
  while (__hip_atomic_load(p, __ATOMIC_RELAXED, __HIP_MEMORY_SCOPE_AGENT) < tgt)
    __builtin_amdgcn_s_sleep(1);
}

// ---------------- weight convert (f32 -> f16, optional column pad) ----------------
__global__ void convert_pad(const float* __restrict__ src, _Float16* __restrict__ dst,
                            int rows, int csrc, int cdst) {
  int i = blockIdx.x * 256 + threadIdx.x;
  if (i >= rows * cdst) return;
  int r = i / cdst, c = i - r * cdst;
  dst[i] = (c < csrc) ? (_Float16)src[(size_t)r * csrc + c] : (_Float16)0.0f;
}

// ---------------- embedding: xt (T, B, INPP) f16 ----------------
__global__ void embed_kernel(const int* __restrict__ context, const int* __restrict__ tags,
                             const float* __restrict__ glove, const float* __restrict__ bio,
                             _Float16* __restrict__ xt) {
  int blk = blockIdx.x;            // t*64 + b
  int t = blk >> 6, b = blk & 63;
  int cid = context[b * Tt + t];   // context (B,T,1)
  int tag = tags[b * Tt + t];      // (B,T)
  _Float16* dst = xt + (size_t)blk * INPP;
  for (int c = threadIdx.x; c < INPP; c += 64) {
    float v = (c < Ee) ? glove[(size_t)cid * Ee + c]
                       : ((c < INP) ? bio[tag * 3 + (c - Ee)] : 0.0f);
    dst[c] = (_Float16)v;
  }
}

// ---------------- persistent GRU recurrence: batch-split chains ----------------
// chain = unit*4 + bg (unit = layer*2+dir, bg = batch group of 16 rows).
// hb slabs: slabIdx(t,unit,bg) holds h_{t-1}[bg*16 .. bg*16+16). Slab t=0 zeros.
// Step t reads slab t, write-through publishes slab t+1. 16 col-blocks per chain.
struct GruParams {
  const _Float16* xt;
  const _Float16* Wx[4];   // ld = 320 (L1) / 512 (L2)
  const _Float16* Wh[4];   // ld = 512
  const float* bih[4];
  const float* bhh[4];
  _Float16* hb;            // fresh slabs, (Tt+1) x 4units x 4bg x SLAB16
  _Float16* allh;          // (B, T, 2H) f16
  float*    h1fin;         // [dir][64][512] fp32 layer-1 final states
};

DEV size_t slabIdx(int t, int unit, int bg) {
  return (((size_t)t * 4 + unit) * 4 + bg) * SLAB16;
}

// stage a 16KB slab (16x512 f16) into LDS, linear dest, inverse-swizzled source.
DEV void stage16k(const char* __restrict__ gsrc, char* lbase, int tid) {
#pragma unroll
  for (int it = 0; it < 4; ++it) {
    int o = (it * 256 + tid) * 16;
    int row = o >> 10, boff = o & 1023;
    int srcOff = (row << 10) | (boff ^ ((row & 7) << 4));
    __builtin_amdgcn_global_load_lds((gas_t)(gsrc + srcOff), (las_t)(lbase + o), 16, 0, 0);
  }
}

// A-fragment read from staged+swizzled 16x512 f16 LDS slab (single M-tile)
DEV f16x8 ldsfrag16(const char* lbase, int k0, int lane) {
  int row = lane & 15;
  int b = (k0 + 8 * (lane >> 4)) * 2;
  int addr = (row << 10) + (b ^ ((row & 7) << 4));
  return *reinterpret_cast<const f16x8*>(lbase + addr);
}

// acc[0..1] += A(16x512 LDS) * W[nt]^T
DEV void hside16(f32x4* acc, const char* lb, const f16x8* w0, const f16x8* w1, int lane) {
#pragma unroll
  for (int k = 0; k < 16; ++k) {
    f16x8 af = ldsfrag16(lb, k * 32, lane);
    acc[0] = __builtin_amdgcn_mfma_f32_16x16x32_f16(af, w0[k], acc[0], 0, 0, 0);
    acc[1] = __builtin_amdgcn_mfma_f32_16x16x32_f16(af, w1[k], acc[1], 0, 0, 0);
  }
}

__global__ __launch_bounds__(256, 1) void gru_persist(GruParams P, unsigned* flags) {
  int unit   = blockIdx.x >> 6;        // layer*2 + dir
  int bg     = (blockIdx.x >> 4) & 3;  // batch group
  int colblk = blockIdx.x & 15;
  int cb     = colblk << 5;            // 32 h-columns per block
  int layer = unit >> 1, dir = unit & 1;
  int chain   = unit * 4 + bg;
  int l1chain = dir  * 4 + bg;
  unsigned* myFlag = flags + ((size_t)chain * 16 + colblk) * 16;  // 64B/flag
  const unsigned* ownF = flags + (size_t)chain   * 16 * 16;
  const unsigned* l1F  = flags + (size_t)l1chain * 16 * 16;

  int tid = threadIdx.x, w = tid >> 6, lane = tid & 63;
  // wave roles: 0 -> r, 1 -> z, 2 -> n_i (x-side only), 3 -> n_h (h-side only)
  int gatebase = (w == 0) ? 0 : (w == 1) ? Hh : 2 * Hh;
  int nrow = gatebase + cb;

  const _Float16* Wx = P.Wx[unit];
  const _Float16* Wh = P.Wh[unit];
  const float* bih = P.bih[unit];
  const float* bhh = P.bhh[unit];

  int col = lane & 15;
  float bv[2];
#pragma unroll
  for (int nt = 0; nt < 2; ++nt) {
    int gcol = cb + nt * 16 + col;
    if      (w == 0) bv[nt] = bih[gcol] + bhh[gcol];
    else if (w == 1) bv[nt] = bih[Hh + gcol] + bhh[Hh + gcol];
    else if (w == 2) bv[nt] = bih[2 * Hh + gcol];
    else             bv[nt] = bhh[2 * Hh + gcol];
  }

  __shared__ _Float16 ldsH[SLAB16];   // 16KB: own hprev (16 rows x 512)
  __shared__ _Float16 ldsX[SLAB16];   // 16KB: L2 only — h1(t)
  __shared__ float gl[4][16][36];     // gate pre-activations
  __shared__ float h32s[16][33];      // block-private fp32 h state (16 rows x 32 cols)
  for (int e = tid; e < 16 * 33; e += 256) ((float*)h32s)[e] = 0.0f;
  __syncthreads();

  int rbase = 4 * (lane >> 4);
  int erow = tid >> 4, ec = (tid & 15) << 1;   // epilogue: 2 cols/thread

#define GLWRITE(ACC)                                              \
  _Pragma("unroll")                                               \
  for (int nt = 0; nt < 2; ++nt)                                  \
    _Pragma("unroll")                                             \
    for (int r = 0; r < 4; ++r)                                   \
      gl[w][rbase + r][nt * 16 + col] = (ACC)[nt][r] + bv[nt];

  union PkU { _Float16 h[2]; unsigned u; };

  if (layer == 0) {
    f16x8 wx[2][10], wh[2][16];
    if (w != 3) {
#pragma unroll
      for (int nt = 0; nt < 2; ++nt)
#pragma unroll
        for (int k = 0; k < 10; ++k) wx[nt][k] = ldfrag(Wx, INPP, nrow + nt * 16, k * 32, lane);
    }
    if (w != 2) {
#pragma unroll
      for (int nt = 0; nt < 2; ++nt)
#pragma unroll
        for (int k = 0; k < 16; ++k) wh[nt][k] = ldfrag(Wh, Hh, nrow + nt * 16, k * 32, lane);
    }
    for (int t = 0; t < Tt; ++t) {
      f32x4 acc[2] = {{0.f,0.f,0.f,0.f},{0.f,0.f,0.f,0.f}};
      // x-side first: overlaps flag propagation from siblings
      if (w != 3) {
        int tt = dir ? (Tt - 1 - t) : t;
        const _Float16* arow = P.xt + (size_t)tt * Bb * INPP
                             + (size_t)(bg * RB + (lane & 15)) * INPP + 8 * (lane >> 4);
#pragma unroll
        for (int k = 0; k < 10; ++k) {
          f16x8 af = *(const f16x8*)(arow + k * 32);
          acc[0] = __builtin_amdgcn_mfma_f32_16x16x32_f16(af, wx[0][k], acc[0], 0, 0, 0);
          acc[1] = __builtin_amdgcn_mfma_f32_16x16x32_f16(af, wx[1][k], acc[1], 0, 0, 0);
        }
      }
      if (tid < 16) pollwait(ownF + tid * 16, (unsigned)t);
      __syncthreads();
      stage16k((const char*)(P.hb + slabIdx(t, unit, bg)), (char*)ldsH, tid);
      asm volatile("s_waitcnt vmcnt(0)" ::: "memory");
      __syncthreads();
      if (w != 2) hside16(acc, (const char*)ldsH, wh[0], wh[1], lane);
      GLWRITE(acc);
      __syncthreads();

      PkU pk; float hv[2];
#pragma unroll
      for (int j = 0; j < 2; ++j) {
        int c = ec + j;
        float rr = sigm(gl[0][erow][c]);
        float zz = sigm(gl[1][erow][c]);
        float nn = tanhf(gl[2][erow][c] + rr * gl[3][erow][c]);
        float hp = h32s[erow][c];
        hv[j] = (1.0f - zz) * nn + zz * hp;
        h32s[erow][c] = hv[j];
        pk.h[j] = (_Float16)hv[j];
      }
      _Float16* hout = P.hb + slabIdx(t + 1, unit, bg) + erow * Hh + cb + ec;
      __hip_atomic_store((unsigned*)hout, pk.u, __ATOMIC_RELAXED, __HIP_MEMORY_SCOPE_AGENT);
      if (t == Tt - 1) {
        float* fp = P.h1fin + ((size_t)dir * Bb + bg * RB + erow) * Hh + cb + ec;
        fp[0] = hv[0]; fp[1] = hv[1];
      }
      asm volatile("s_waitcnt vmcnt(0)" ::: "memory");   // publish drained to coherence point
      __syncthreads();
      if (tid == 0)
        __hip_atomic_store(myFlag, (unsigned)(t + 1), __ATOMIC_RELAXED, __HIP_MEMORY_SCOPE_AGENT);
    }
  } else {
    f16x8 wx[2][16], wh[2][16];
    if (w != 3) {
#pragma unroll
      for (int nt = 0; nt < 2; ++nt)
#pragma unroll
        for (int k = 0; k < 16; ++k) wx[nt][k] = ldfrag(Wx, Hh, nrow + nt * 16, k * 32, lane);
    }
    if (w != 2) {
#pragma unroll
      for (int nt = 0; nt < 2; ++nt)
#pragma unroll
        for (int k = 0; k < 16; ++k) wh[nt][k] = ldfrag(Wh, Hh, nrow + nt * 16, k * 32, lane);
    }
    for (int t = 0; t < Tt; ++t) {
      // wait: own chain siblings >= t AND producing L1 chain >= t+1 (h1(t) complete)
      if (tid < 16)      pollwait(ownF + tid * 16, (unsigned)t);
      else if (tid < 32) pollwait(l1F + (tid - 16) * 16, (unsigned)(t + 1));
      __syncthreads();
      stage16k((const char*)(P.hb + slabIdx(t + 1, dir, bg)), (char*)ldsX, tid);  // h1(t)
      stage16k((const char*)(P.hb + slabIdx(t, unit, bg)),    (char*)ldsH, tid);  // own hprev
      asm volatile("s_waitcnt vmcnt(0)" ::: "memory");
      __syncthreads();

      f32x4 acc[2] = {{0.f,0.f,0.f,0.f},{0.f,0.f,0.f,0.f}};
      if (w != 3) hside16(acc, (const char*)ldsX, wx[0], wx[1], lane);
      if (w != 2) hside16(acc, (const char*)ldsH, wh[0], wh[1], lane);
      GLWRITE(acc);
      __syncthreads();

      PkU pk; float hv[2];
#pragma unroll
      for (int j = 0; j < 2; ++j) {
        int c = ec + j;
        float rr = sigm(gl[0][erow][c]);
        float zz = sigm(gl[1][erow][c]);
        float nn = tanhf(gl[2][erow][c] + rr * gl[3][erow][c]);
        float hp = h32s[erow][c];
        hv[j] = (1.0f - zz) * nn + zz * hp;
        h32s[erow][c] = hv[j];
        pk.h[j] = (_Float16)hv[j];
      }
      _Float16* hout = P.hb + slabIdx(t + 1, unit, bg) + erow * Hh + cb + ec;
      __hip_atomic_store((unsigned*)hout, pk.u, __ATOMIC_RELAXED, __HIP_MEMORY_SCOPE_AGENT);

      asm volatile("s_waitcnt vmcnt(0)" ::: "memory");
      __syncthreads();
      if (tid == 0)
        __hip_atomic_store(myFlag, (unsigned)(t + 1), __ATOMIC_RELAXED, __HIP_MEMORY_SCOPE_AGENT);
      // allh publication off the critical publish path (consumed post-kernel)
      *(unsigned*)(P.allh + ((size_t)(bg * RB + erow) * Tt + t) * D2H + dir * Hh + cb + ec) = pk.u;
    }
  }
#undef GLWRITE
}

// ---------------- tiled TN GEMM: C = [A|A2](MxK, K-major) * B(NxK, K-major)^T ----------------
struct TArgs {
  const _Float16* A; const _Float16* A2; const _Float16* B;
  _Float16* Ch; float* Cf;
  const float* bias;
  int lda, ldb, ldc, K, Ksplit;
  long long sAz, sBz, sCz;
};

template<int MODE>  // 0: f16 out; 1: f16 out + bias; 2: f32 out
__global__ __launch_bounds__(256) void gemm_tiled(TArgs g) {
  int z = blockIdx.z;
  const _Float16* A  = g.A + (size_t)z * g.sAz;
  const _Float16* Bm = g.B + (size_t)z * g.sBz;
  int m0 = blockIdx.y * 128, n0 = blockIdx.x * 128;
  int tid = threadIdx.x, lane = tid & 63;
  int wr = (tid >> 7) & 1, wc = (tid >> 6) & 1;  // wave grid 2x2

  __shared__ _Float16 sA[2][128 * 64];
  __shared__ _Float16 sB[2][128 * 64];

  int ldab = g.lda * 2, ldbb = g.ldb * 2;

#define STAGE(buf, kt)                                                                   \
  {                                                                                      \
    int k0 = (kt) * 64;                                                                  \
    const _Float16* Asrc = A; int ka = k0;                                               \
    if (k0 >= g.Ksplit) { Asrc = g.A2; ka = k0 - g.Ksplit; }                             \
    const char* ab = (const char*)(Asrc + (size_t)m0 * g.lda + ka);                      \
    const char* bb = (const char*)(Bm  + (size_t)n0 * g.ldb + k0);                       \
    char* la = (char*)sA[buf]; char* lb = (char*)sB[buf];                                \
    _Pragma("unroll")                                                                    \
    for (int it = 0; it < 4; ++it) {                                                     \
      int o = (it * 256 + tid) * 16;                                                     \
      int row = o >> 7, boff = o & 127;                                                  \
      int sw = boff ^ ((row & 7) << 4);                                                  \
      __builtin_amdgcn_global_load_lds((gas_t)(ab + (size_t)row * ldab + sw),            \
                                       (las_t)(la + o), 16, 0, 0);                       \
      __builtin_amdgcn_global_load_lds((gas_t)(bb + (size_t)row * ldbb + sw),            \
                                       (las_t)(lb + o), 16, 0, 0);                       \
    }                                                                                    \
  }

  f32x4 acc[4][4] = {};
  int nkt = g.K / 64;
  STAGE(0, 0);
  asm volatile("s_waitcnt vmcnt(0)" ::: "memory");
  __syncthreads();

  int cbyte = (lane >> 4) << 4;  // 0,16,32,48
  for (int kt = 0; kt < nkt; ++kt) {
    int buf = kt & 1;
    if (kt + 1 < nkt) STAGE(buf ^ 1, kt + 1);
    const char* la = (const char*)sA[buf];
    const char* lb = (const char*)sB[buf];
    f16x8 af[2][4], bfr[2][4];
#pragma unroll
    for (int kk = 0; kk < 2; ++kk) {
#pragma unroll
      for (int mt = 0; mt < 4; ++mt) {
        int r = wr * 64 + mt * 16 + (lane & 15);
        int c = kk * 64 + cbyte;
        af[kk][mt] = *(const f16x8*)(la + r * 128 + (c ^ ((r & 7) << 4)));
      }
#pragma unroll
      for (int nt = 0; nt < 4; ++nt) {
        int r = wc * 64 + nt * 16 + (lane & 15);
        int c = kk * 64 + cbyte;
        bfr[kk][nt] = *(const f16x8*)(lb + r * 128 + (c ^ ((r & 7) << 4)));
      }
    }
#pragma unroll
    for (int kk = 0; kk < 2; ++kk)
#pragma unroll
      for (int mt = 0; mt < 4; ++mt)
#pragma unroll
        for (int nt = 0; nt < 4; ++nt)
          acc[mt][nt] = __builtin_amdgcn_mfma_f32_16x16x32_f16(af[kk][mt], bfr[kk][nt], acc[mt][nt], 0, 0, 0);
    asm volatile("s_waitcnt vmcnt(0)" ::: "memory");
    __syncthreads();
  }
#undef STAGE

  int rb = 4 * (lane >> 4);
#pragma unroll
  for (int nt = 0; nt < 4; ++nt) {
    int col = n0 + wc * 64 + nt * 16 + (lane & 15);
    float bv = (MODE == 1) ? g.bias[col] : 0.0f;
#pragma unroll
    for (int mt = 0; mt < 4; ++mt) {
#pragma unroll
      for (int r = 0; r < 4; ++r) {
        int row = m0 + wr * 64 + mt * 16 + rb + r;
        size_t idx = (size_t)z * g.sCz + (size_t)row * g.ldc + col;
        float v = acc[mt][nt][r] + bv;
        if (MODE == 2) g.Cf[idx] = v; else g.Ch[idx] = (_Float16)v;
      }
    }
  }
}

// ---------------- row softmax: scores f32 (.,512) -> p f16 ----------------
__global__ __launch_bounds__(256) void softmax_rows(const float* __restrict__ sc, _Float16* __restrict__ p) {
  int row = blockIdx.x * 4 + (threadIdx.x >> 6);
  int lane = threadIdx.x & 63;
  const float* s = sc + (size_t)row * 512 + lane * 8;
  float v[8];
  float4 q0 = *(const float4*)s, q1 = *(const float4*)(s + 4);
  v[0]=q0.x; v[1]=q0.y; v[2]=q0.z; v[3]=q0.w; v[4]=q1.x; v[5]=q1.y; v[6]=q1.z; v[7]=q1.w;
  float mx = v[0];
#pragma unroll
  for (int j = 1; j < 8; ++j) mx = fmaxf(mx, v[j]);
  for (int o = 32; o; o >>= 1) mx = fmaxf(mx, __shfl_xor(mx, o));
  float sum = 0.f;
#pragma unroll
  for (int j = 0; j < 8; ++j) { v[j] = expf(v[j] - mx); sum += v[j]; }
  for (int o = 32; o; o >>= 1) sum += __shfl_xor(sum, o);
  float inv = 1.0f / sum;
  _Float16* pd = p + (size_t)row * 512 + lane * 8;
#pragma unroll
  for (int j = 0; j < 8; ++j) pd[j] = (_Float16)(v[j] * inv);
}

// ---------------- per-batch transpose: allhT[b][d][t] = allh[b][t][d] ----------------
__global__ void transpose_bt(const _Float16* __restrict__ allh, _Float16* __restrict__ allhT) {
  __shared__ _Float16 tile[32][33];
  int b = blockIdx.z;
  int d0 = blockIdx.x * 32, t0 = blockIdx.y * 32;
  int tx = threadIdx.x, ty = threadIdx.y;  // (32, 8)
  const _Float16* in = allh + (size_t)b * Tt * D2H;
  _Float16* outp = allhT + (size_t)b * D2H * Tt;
#pragma unroll
  for (int j = 0; j < 4; ++j)
    tile[ty + 8 * j][tx] = in[(size_t)(t0 + ty + 8 * j) * D2H + d0 + tx];
  __syncthreads();
#pragma unroll
  for (int j = 0; j < 4; ++j)
    outp[(size_t)(d0 + ty + 8 * j) * Tt + t0 + tx] = tile[tx][ty + 8 * j];
}

// ---------------- gating epilogue: attn = g*f + (1-g)*allh ----------------
__global__ __launch_bounds__(256) void gating(const _Float16* __restrict__ gfpre,
                                              const _Float16* __restrict__ allh,
                                              const float* __restrict__ bg,
                                              const float* __restrict__ bfv,
                                              float* __restrict__ out_attn) {
  int i = blockIdx.x * 256 + threadIdx.x;   // over (B*T) * 128 groups
  int m = i >> 7, c0 = (i & 127) << 3;
  f16x8 gv = *(const f16x8*)(gfpre + (size_t)m * 2048 + c0);
  f16x8 fv = *(const f16x8*)(gfpre + (size_t)m * 2048 + 1024 + c0);
  f16x8 ah = *(const f16x8*)(allh + (size_t)m * D2H + c0);
  float res[8];
#pragma unroll
  for (int j = 0; j < 8; ++j) {
    float gg = sigm((float)gv[j] + bg[c0 + j]);
    float ff = tanhf((float)fv[j] + bfv[c0 + j]);
    res[j] = gg * ff + (1.0f - gg) * (float)ah[j];
  }
  float4* dst = (float4*)(out_attn + (size_t)m * D2H + c0);
  dst[0] = make_float4(res[0], res[1], res[2], res[3]);
  dst[1] = make_float4(res[4], res[5], res[6], res[7]);
}

// ---------------- final concat output ----------------
__global__ void write_concat(const float* __restrict__ h1fin, float* __restrict__ out) {
  int i = blockIdx.x * 256 + threadIdx.x;
  if (i >= Bb * D2H) return;
  int b = i >> 10, c = i & 1023;
  out[i] = (c < Hh) ? h1fin[(size_t)b * Hh + c] : h1fin[(size_t)(Bb + b) * Hh + (c - Hh)];
}

// =============================== host ===============================
extern "C" void kernel_launch(void* const* d_in, const int* in_sizes, int n_in,
                              void* d_out, int out_size, void* d_ws, size_t ws_size,
                              hipStream_t stream) {
  const int*   context = (const int*)d_in[0];
  const int*   tags    = (const int*)d_in[1];
  const float* glove   = (const float*)d_in[2];
  const float* bio     = (const float*)d_in[3];
  const float* b_lin   = (const float*)d_in[21];
  const float* b_g     = (const float*)d_in[23];
  const float* b_f     = (const float*)d_in[25];

  char* ws = (char*)d_ws;
  size_t off = 0;
  auto carve = [&](size_t bytes) -> void* {
    void* pp = ws + off;
    off = (off + bytes + 255) & ~(size_t)255;
    return pp;
  };

  _Float16* xt = (_Float16*)carve((size_t)Tt * Bb * INPP * 2);
  _Float16 *Wx16[2][2], *Wh16[2][2];
  Wx16[0][0] = (_Float16*)carve((size_t)1536 * 320 * 2);
  Wx16[1][0] = (_Float16*)carve((size_t)1536 * 320 * 2);
  Wx16[0][1] = (_Float16*)carve((size_t)1536 * 512 * 2);
  Wx16[1][1] = (_Float16*)carve((size_t)1536 * 512 * 2);
  for (int d = 0; d < 2; ++d)
    for (int l = 0; l < 2; ++l) Wh16[d][l] = (_Float16*)carve((size_t)1536 * 512 * 2);
  _Float16* wlin = (_Float16*)carve((size_t)1024 * 1024 * 2);
  _Float16* wgf  = (_Float16*)carve((size_t)2048 * 2048 * 2);
  _Float16* allh  = (_Float16*)carve((size_t)Bb * Tt * D2H * 2);      // 64 MiB
  _Float16* allhT = (_Float16*)carve((size_t)Bb * Tt * D2H * 2);      // 64 MiB (hb / gf_pre alias)
  float*    scores = (float*)carve((size_t)Bb * Tt * Tt * 4);          // 64 MiB (hb / gf_pre alias)
  _Float16* pmat   = (_Float16*)carve((size_t)Bb * Tt * Tt * 2);       // 32 MiB (hb tail alias)
  _Float16* qctx   = (_Float16*)carve((size_t)Bb * Tt * D2H * 2);      // q, then ctx
  float*    h1fin  = (float*)carve((size_t)2 * Bb * Hh * 4);
  unsigned* flags  = (unsigned*)carve((size_t)16 * 16 * 16 * 4);       // 16KB, 64B per flag

  // hb: (Tt+1)*16*SLAB16*2 = 128.25 MiB, aliases allhT+scores+pmat-head (dead during recurrence)
  _Float16* hb = allhT;
  // gf_pre: 32768 x 2048 f16 = 128 MiB, aliases allhT+scores (dead by gf time)
  _Float16* gfpre = allhT;

  hipMemsetAsync(hb, 0, (size_t)16 * SLAB16 * 2, stream);        // slab t=0 (16 chains) = 0
  hipMemsetAsync(flags, 0, (size_t)16 * 16 * 16 * 4, stream);    // progress flags

  auto conv = [&](const void* src, _Float16* dst, int rows, int csrc, int cdst) {
    int total = rows * cdst;
    convert_pad<<<(total + 255) / 256, 256, 0, stream>>>((const float*)src, dst, rows, csrc, cdst);
  };
  conv(d_in[4],  Wx16[0][0], 1536, 303, 320);
  conv(d_in[12], Wx16[1][0], 1536, 303, 320);
  conv(d_in[8],  Wx16[0][1], 1536, 512, 512);
  conv(d_in[16], Wx16[1][1], 1536, 512, 512);
  conv(d_in[5],  Wh16[0][0], 1536, 512, 512);
  conv(d_in[13], Wh16[1][0], 1536, 512, 512);
  conv(d_in[9],  Wh16[0][1], 1536, 512, 512);
  conv(d_in[17], Wh16[1][1], 1536, 512, 512);
  conv(d_in[20], wlin, 1024, 1024, 1024);
  conv(d_in[22], wgf, 1024, 2048, 2048);
  conv(d_in[24], wgf + (size_t)1024 * 2048, 1024, 2048, 2048);

  embed_kernel<<<Tt * Bb, 64, 0, stream>>>(context, tags, glove, bio, xt);

  GruParams GP;
  GP.xt = xt;
  // unit = layer*2 + dir
  GP.Wx[0] = Wx16[0][0]; GP.Wx[1] = Wx16[1][0]; GP.Wx[2] = Wx16[0][1]; GP.Wx[3] = Wx16[1][1];
  GP.Wh[0] = Wh16[0][0]; GP.Wh[1] = Wh16[1][0]; GP.Wh[2] = Wh16[0][1]; GP.Wh[3] = Wh16[1][1];
  GP.bih[0] = (const float*)d_in[6];  GP.bhh[0] = (const float*)d_in[7];
  GP.bih[1] = (const float*)d_in[14]; GP.bhh[1] = (const float*)d_in[15];
  GP.bih[2] = (const float*)d_in[10]; GP.bhh[2] = (const float*)d_in[11];
  GP.bih[3] = (const float*)d_in[18]; GP.bhh[3] = (const float*)d_in[19];
  GP.hb = hb;
  GP.allh = allh;
  GP.h1fin = h1fin;

  gru_persist<<<256, 256, 0, stream>>>(GP, flags);

  TArgs ga;
  // q = all_h @ W_lin^T + b_lin -> f16 qctx
  ga.A = allh; ga.A2 = allh; ga.B = wlin;
  ga.Ch = qctx; ga.Cf = nullptr; ga.bias = b_lin;
  ga.lda = 1024; ga.ldb = 1024; ga.ldc = 1024; ga.K = 1024; ga.Ksplit = 1 << 30;
  ga.sAz = 0; ga.sBz = 0; ga.sCz = 0;
  gemm_tiled<1><<<dim3(8, 256, 1), 256, 0, stream>>>(ga);

  // scores[b] = q[b] @ all_h[b]^T -> f32
  ga.A = qctx; ga.A2 = qctx; ga.B = allh;
  ga.Ch = nullptr; ga.Cf = scores; ga.bias = nullptr;
  ga.lda = 1024; ga.ldb = 1024; ga.ldc = 512; ga.K = 1024; ga.Ksplit = 1 << 30;
  ga.sAz = (long long)512 * 1024; ga.sBz = (long long)512 * 1024; ga.sCz = (long long)512 * 512;
  gemm_tiled<2><<<dim3(4, 4, 64), 256, 0, stream>>>(ga);

  softmax_rows<<<(Bb * Tt) / 4, 256, 0, stream>>>(scores, pmat);

  transpose_bt<<<dim3(32, 16, 64), dim3(32, 8), 0, stream>>>(allh, allhT);

  // ctx[b] = p[b] @ (all_hT[b])^T -> f16 (overwrites q in qctx)
  ga.A = pmat; ga.A2 = pmat; ga.B = allhT;
  ga.Ch = qctx; ga.Cf = nullptr; ga.bias = nullptr;
  ga.lda = 512; ga.ldb = 512; ga.ldc = 1024; ga.K = 512; ga.Ksplit = 1 << 30;
  ga.sAz = (long long)512 * 512; ga.sBz = (long long)1024 * 512; ga.sCz = (long long)512 * 1024;
  gemm_tiled<0><<<dim3(8, 4, 64), 256, 0, stream>>>(ga);

  // gf_pre = [ctx | all_h] @ Wgf^T -> f16 (overwrites allhT+scores region)
  ga.A = qctx; ga.A2 = allh; ga.B = wgf;
  ga.Ch = gfpre; ga.Cf = nullptr; ga.bias = nullptr;
  ga.lda = 1024; ga.ldb = 2048; ga.ldc = 2048; ga.K = 2048; ga.Ksplit = 1024;
  ga.sAz = 0; ga.sBz = 0; ga.sCz = 0;
  gemm_tiled<0><<<dim3(16, 256, 1), 256, 0, stream>>>(ga);

  float* out_attn = (float*)d_out + (size_t)Bb * D2H;
  gating<<<(Bb * Tt * 128) / 256, 256, 0, stream>>>(gfpre, allh, b_g, b_f, out_attn);

  write_concat<<<(Bb * D2H + 255) / 256, 256, 0, stream>>>(h1fin, (float*)d_out);
}